// Round 7
// baseline (239.998 us; speedup 1.0000x reference)
//
#include <hip/hip_runtime.h>
#include <hip/hip_bf16.h>
#include <math.h>

#define B_  16
#define L_  3600
#define LAT 64
#define DM  128
#define DI  256
#define DS  16
#define DR  8

#define TT  45    // K1 time-tile == scan chunk length
#define NT  80    // 3600/45 tiles == chunks
#define NC  80
#define TC  45
#define THR (-20.0f)   // exp(a*S) < exp(-20) ~ 2e-9 -> negligible

typedef __bf16 v8bf __attribute__((ext_vector_type(8)));
typedef float  v4f  __attribute__((ext_vector_type(4)));
typedef unsigned short v8us __attribute__((ext_vector_type(8)));

#define MFMA16(A, Bf, C) __builtin_amdgcn_mfma_f32_16x16x32_bf16((A), (Bf), (C), 0, 0, 0)

__device__ __forceinline__ float siluf(float v) {
    return v * __builtin_amdgcn_rcpf(1.0f + __expf(-v));
}
__device__ __forceinline__ float softplusf(float v) {
    float r = __logf(1.0f + __expf(v));
    return (v > 15.0f) ? v : r;
}
__device__ __forceinline__ float bf2f(unsigned short u) {
    unsigned int x = ((unsigned int)u) << 16;
    return __builtin_bit_cast(float, x);
}
__device__ __forceinline__ unsigned short f2bf(float f) {
    __hip_bfloat16 h = __float2bfloat16(f);
    return __builtin_bit_cast(unsigned short, h);
}

// ---------------------------------------------------------------- K0: W1 = in_proj_x @ emb_w (+ hi/lo bf16), b1; pre-swizzled x_proj hi/lo
__global__ __launch_bounds__(64) void k0_combine(
    const float* __restrict__ in_proj_w, const float* __restrict__ emb_w,
    const float* __restrict__ emb_b, const float* __restrict__ x_proj_w,
    float* __restrict__ W1, float* __restrict__ b1,
    unsigned short* __restrict__ W1h, unsigned short* __restrict__ W1l,
    unsigned short* __restrict__ xwh, unsigned short* __restrict__ xwl)
{
    int blk = blockIdx.x, k = threadIdx.x;
    if (blk < DI) {
        int d = blk;
        const float* row = in_proj_w + (size_t)d * DM;
        float acc = 0.f;
        for (int m = 0; m < DM; ++m) acc += row[m] * emb_w[m * LAT + k];
        W1[d * LAT + k] = acc;
        unsigned short h = f2bf(acc);
        W1h[d * LAT + k] = h;
        W1l[d * LAT + k] = f2bf(acc - bf2f(h));
        if (k == 0) {
            float ab = 0.f;
            for (int m = 0; m < DM; ++m) ab += row[m] * emb_b[m];
            b1[d] = ab;
        }
    } else {
        int j = blk - DI;   // 0..23
        int sw = (j & 7) << 3;
        #pragma unroll
        for (int q = 0; q < 4; ++q) {
            int c = k * 4 + q;
            float v = x_proj_w[(size_t)j * DI + c];
            unsigned short h = f2bf(v);
            int idx = j * 256 + (c ^ sw);
            xwh[idx] = h;
            xwl[idx] = f2bf(v - bf2f(h));
        }
    }
}

// ---------------------------------------------------------------- K1: MFMA front-end + dt + chunk dt-sums
// 1 tile/block, 1280 blocks; LDS 33,056 B, launch_bounds(256,4) -> 4 blocks/CU
// (VGPR cap 128, no spill), 1.25 dispatch rounds.
// LDS byte map (smem region):
//   phase A/conv : [0,16448) xpre f32[16][257] | [16448,22592) z-hi | [22592,28736) z-lo
//   phase B      : [0,24576) xt16 u16[48][256] swz (xw frags read from GLOBAL, L2-hot)
// Bssm staged in bl[45][16] LDS, written coalesced in phase C (kills 16x write-amp).
__global__ __launch_bounds__(256, 4) void k1_front(
    const float* __restrict__ z, const float* __restrict__ conv_w,
    const float* __restrict__ conv_b, const float* __restrict__ dt_proj_w,
    const float* __restrict__ dt_proj_b,
    const unsigned short* __restrict__ W1h, const unsigned short* __restrict__ W1l,
    const unsigned short* __restrict__ xwh, const unsigned short* __restrict__ xwl,
    const float* __restrict__ b1,
    float* __restrict__ Bssm, float* __restrict__ Dcs,
    unsigned int* __restrict__ xd, float* __restrict__ hlast)
{
    __shared__ __align__(16) unsigned char smem[28736];
    __shared__ float dtl[TT][8];
    __shared__ float bl[TT][DS];
    float* xpre = (float*)smem;                              // [16][257] f32
    unsigned short* zth = (unsigned short*)(smem + 16448);   // 3072 u16
    unsigned short* ztl = (unsigned short*)(smem + 22592);   // 3072 u16
    unsigned short* xt16 = (unsigned short*)smem;            // [48][256] swz

    int b = blockIdx.y, tile = blockIdx.x;
    int t0 = tile * TT;
    int t0m3 = t0 - 3;
    int tid = threadIdx.x;
    int lane = tid & 63, wid = tid >> 6;
    int l15 = lane & 15, l4 = lane >> 4;

    // zero hlast (poisoned workspace) -- before k3b runs
    if (tile == 0) {
        float4 z4 = make_float4(0.f, 0.f, 0.f, 0.f);
        float4* hl4 = (float4*)(hlast + (size_t)b * (DS * DI));
        #pragma unroll
        for (int i = 0; i < 4; ++i) hl4[tid + i * 256] = z4;
    }

    // per-thread conv + dt params (channel d = tid)
    float4 cw = *(const float4*)(conv_w + tid * 4);
    float cb = conv_b[tid];
    float bias = b1[tid];
    float4 dwA = *(const float4*)(dt_proj_w + (size_t)tid * DR);
    float4 dwB = *(const float4*)(dt_proj_w + (size_t)tid * DR + 4);
    float dbias = dt_proj_b[tid];

    // ---- B-frags for phase A from W1 hi/lo (once per block)
    v8bf wh[4][2], wl[4][2];
    int d0w = wid * 64;
    {
        #pragma unroll
        for (int nt = 0; nt < 4; ++nt) {
            int dr = d0w + nt * 16 + l15;
            #pragma unroll
            for (int kb = 0; kb < 2; ++kb) {
                int k0 = kb * 32 + l4 * 8;
                wh[nt][kb] = __builtin_bit_cast(v8bf, *(const v8us*)(W1h + (size_t)dr * LAT + k0));
                wl[nt][kb] = __builtin_bit_cast(v8bf, *(const v8us*)(W1l + (size_t)dr * LAT + k0));
            }
        }
    }

    // ---- stage z tile (48 rows incl history) as hi/lo bf16, XOR-swizzled rows
    {
        const float* zb = z + (size_t)b * L_ * LAT;
        for (int i = tid; i < 48 * 8; i += 256) {   // (row, 8-elem slot)
            int r = i >> 3, s = i & 7;
            int tg = t0m3 + r;
            float f[8];
            if (tg >= 0) {
                float4 u = *(const float4*)(zb + (size_t)tg * LAT + s * 8);
                float4 v = *(const float4*)(zb + (size_t)tg * LAT + s * 8 + 4);
                f[0]=u.x; f[1]=u.y; f[2]=u.z; f[3]=u.w; f[4]=v.x; f[5]=v.y; f[6]=v.z; f[7]=v.w;
            } else {
                #pragma unroll
                for (int q = 0; q < 8; ++q) f[q] = 0.f;
            }
            v8us hh, ll;
            #pragma unroll
            for (int q = 0; q < 8; ++q) {
                unsigned short h = f2bf(f[q]);
                hh[q] = h;
                ll[q] = f2bf(f[q] - bf2f(h));
            }
            int idx = r * 64 + ((s * 8) ^ ((r & 7) << 3));   // u16 units, 16B slots
            *(v8us*)&zth[idx] = hh;
            *(v8us*)&ztl[idx] = ll;
        }
    }
    __syncthreads();

    float xr[TT];
    float p0 = 0.f, p1 = 0.f, p2 = 0.f;

    // ---- phase A in 3 sub-phases of 16 rows: MFMA(mt) -> bar -> conv -> bar
    #pragma unroll
    for (int mt = 0; mt < 3; ++mt) {
        {   // MFMA m-tile mt (writes xpre rows 0..15)
            int r = mt * 16 + l15;
            int sw = (r & 7) << 3;
            int kb0 = l4 * 8;
            v8bf ah0 = __builtin_bit_cast(v8bf, *(const v8us*)&zth[r * 64 + (kb0 ^ sw)]);
            v8bf ah1 = __builtin_bit_cast(v8bf, *(const v8us*)&zth[r * 64 + ((32 + kb0) ^ sw)]);
            v8bf al0 = __builtin_bit_cast(v8bf, *(const v8us*)&ztl[r * 64 + (kb0 ^ sw)]);
            v8bf al1 = __builtin_bit_cast(v8bf, *(const v8us*)&ztl[r * 64 + ((32 + kb0) ^ sw)]);
            int rr = l4 * 4;
            #pragma unroll
            for (int nt = 0; nt < 4; ++nt) {
                v4f acc = {0.f, 0.f, 0.f, 0.f};
                acc = MFMA16(ah0, wh[nt][0], acc);
                acc = MFMA16(ah1, wh[nt][1], acc);
                acc = MFMA16(ah0, wl[nt][0], acc);
                acc = MFMA16(ah1, wl[nt][1], acc);
                acc = MFMA16(al0, wh[nt][0], acc);
                acc = MFMA16(al1, wh[nt][1], acc);
                int cc = d0w + nt * 16 + l15;
                xpre[(rr + 0) * 257 + cc] = acc[0];
                xpre[(rr + 1) * 257 + cc] = acc[1];
                xpre[(rr + 2) * 257 + cc] = acc[2];
                xpre[(rr + 3) * 257 + cc] = acc[3];
            }
        }
        __syncthreads();
        {   // conv rows mt*16 .. mt*16+15
            int d = tid;
            if (mt == 0) {
                p0 = xpre[0 * 257 + d] + ((t0m3 + 0 >= 0) ? bias : 0.f);
                p1 = xpre[1 * 257 + d] + ((t0m3 + 1 >= 0) ? bias : 0.f);
                p2 = xpre[2 * 257 + d] + ((t0m3 + 2 >= 0) ? bias : 0.f);
                #pragma unroll
                for (int r = 3; r < 16; ++r) {
                    float cur = xpre[r * 257 + d] + bias;
                    float xc = cw.x * p0 + cw.y * p1 + cw.z * p2 + cw.w * cur + cb;
                    xr[r - 3] = siluf(xc);
                    p0 = p1; p1 = p2; p2 = cur;
                }
            } else {
                int rbase = mt * 16;
                #pragma unroll
                for (int q = 0; q < 16; ++q) {
                    float cur = xpre[q * 257 + d] + bias;
                    float xc = cw.x * p0 + cw.y * p1 + cw.z * p2 + cw.w * cur + cb;
                    xr[rbase + q - 3] = siluf(xc);
                    p0 = p1; p1 = p2; p2 = cur;
                }
            }
        }
        __syncthreads();
    }

    // ---- write xt bf16 (swizzled; xpre & z-tile now dead)
    {
        int d = tid;
        #pragma unroll
        for (int t = 0; t < TT; ++t)
            xt16[t * 256 + (d ^ ((t & 7) << 3))] = f2bf(xr[t]);
        #pragma unroll
        for (int t = TT; t < 48; ++t)
            xt16[t * 256 + (d ^ ((t & 7) << 3))] = 0;
    }
    __syncthreads();

    // ---- phase B MFMA: x_dbl[t][j] = sum_k xt[t][k] * x_proj_w[j][k], j = 0..23
    //      B-frags (xw hi/lo) read directly from GLOBAL (pre-swizzled by k0; 24 KB, L2-hot)
    if (wid < 3) {
        int mt = wid;
        int rA = mt * 16 + l15;
        int swA = (rA & 7) << 3;
        int jc0 = l15;
        int jc1 = 16 + l15; if (jc1 > 23) jc1 = 23;   // clamp (outputs >=24 discarded)
        v4f acc0 = {0.f, 0.f, 0.f, 0.f}, acc1 = {0.f, 0.f, 0.f, 0.f};
        #pragma unroll
        for (int kb = 0; kb < 8; ++kb) {
            int k0 = kb * 32 + l4 * 8;
            v8bf xa  = __builtin_bit_cast(v8bf, *(const v8us*)&xt16[rA * 256 + (k0 ^ swA)]);
            int s0 = k0 ^ ((jc0 & 7) << 3);
            int s1 = k0 ^ ((jc1 & 7) << 3);
            v8bf b0h = __builtin_bit_cast(v8bf, *(const v8us*)(xwh + jc0 * 256 + s0));
            v8bf b0l = __builtin_bit_cast(v8bf, *(const v8us*)(xwl + jc0 * 256 + s0));
            v8bf b1h = __builtin_bit_cast(v8bf, *(const v8us*)(xwh + jc1 * 256 + s1));
            v8bf b1l = __builtin_bit_cast(v8bf, *(const v8us*)(xwl + jc1 * 256 + s1));
            acc0 = MFMA16(xa, b0h, acc0);
            acc0 = MFMA16(xa, b0l, acc0);
            acc1 = MFMA16(xa, b1h, acc1);
            acc1 = MFMA16(xa, b1l, acc1);
        }
        int rr = mt * 16 + l4 * 4;
        #pragma unroll
        for (int reg = 0; reg < 4; ++reg) {
            int t = rr + reg;
            if (t < TT) {
                float v0 = acc0[reg], v1 = acc1[reg];
                if (l15 < 8) {
                    dtl[t][l15] = v0;          // dt_in cols 0..7
                    bl[t][8 + l15] = v1;       // B cols 8..15 (j = 16..23)
                } else {
                    bl[t][l15 - 8] = v0;       // B cols 0..7 (j = 8..15)
                }
            }
        }
    }
    __syncthreads();

    // ---- phase C: Bssm coalesced store (from bl) + dt = softplus(...) packed store + per-tile sum
    {
        // coalesced Bssm: 720 consecutive floats, 256B per wave-store
        float* Bout = Bssm + ((size_t)b * L_ + t0) * DS;
        #pragma unroll
        for (int i = tid; i < TT * DS; i += 256)
            Bout[i] = bl[i >> 4][i & 15];

        int d = tid;
        unsigned int* xdout = xd + ((size_t)b * L_ + t0) * DI + d;
        float S = 0.f;
        #pragma unroll 5
        for (int t = 0; t < TT; ++t) {
            float4 u = *(const float4*)&dtl[t][0];
            float4 v = *(const float4*)&dtl[t][4];
            float r = dbias + u.x*dwA.x + u.y*dwA.y + u.z*dwA.z + u.w*dwA.w
                            + v.x*dwB.x + v.y*dwB.y + v.z*dwB.z + v.w*dwB.w;
            float dt = softplusf(r);
            unsigned int pack = ((unsigned int)f2bf(dt) << 16) | (unsigned int)f2bf(xr[t]);
            xdout[(size_t)t * DI] = pack;
            S += dt;
        }
        Dcs[((size_t)b * NC + tile) * DI + d] = S;
    }
}

// ---------------------------------------------------------------- K3b: streaming suffix reduction (computes own suffix R from Dcs);
//      atomic combine into hlast
__global__ __launch_bounds__(512) void k3b_scan(
    const unsigned int* __restrict__ xd,
    const float* __restrict__ Bssm, const float* __restrict__ A_log,
    const float* __restrict__ Dcs, float* __restrict__ hlast)
{
    int c = blockIdx.x, dg = blockIdx.y, b = blockIdx.z;
    int tid = threadIdx.x;
    int dh = tid & 31;
    int s  = ((tid >> 6) << 1) | ((tid >> 5) & 1);
    int d  = dg * 32 + dh;

    float a = -__expf(A_log[d * DS + s]);

    // suffix sum of chunk dt-sums, descending (bit-identical to old k3a2 order)
    float R = 0.f;
    {
        const float* Dp = Dcs + (size_t)b * NC * DI + d;
        for (int cc = NC - 1; cc > c; --cc) R += Dp[(size_t)cc * DI];
    }

    float H = 0.f;
    float S_run = R;
    if (!__all(a * R < THR)) {
        int t0 = c * TC;
        const unsigned int* xp = xd + ((size_t)b * L_ + t0) * DI + d;
        const float* Bp = Bssm + ((size_t)b * L_ + t0) * DS + s;
        {   // t = TT-1 single (45 = 11*4 + 1)
            unsigned int u4 = xp[(TC-1)*DI];
            float x4 = bf2f((unsigned short)(u4 & 0xffff));
            float d4 = bf2f((unsigned short)(u4 >> 16));
            float B4 = Bp[(TC-1)*DS];
            float e = __expf(a * S_run); H = fmaf(e * d4 * x4, B4, H); S_run += d4;
        }
        for (int j = TC - 5; j >= 0; j -= 4) {
            unsigned int u3 = xp[(j+3)*DI];
            unsigned int u2 = xp[(j+2)*DI];
            unsigned int u1 = xp[(j+1)*DI];
            unsigned int u0 = xp[(j+0)*DI];
            float x3 = bf2f((unsigned short)(u3 & 0xffff)), d3 = bf2f((unsigned short)(u3 >> 16));
            float x2 = bf2f((unsigned short)(u2 & 0xffff)), d2 = bf2f((unsigned short)(u2 >> 16));
            float x1 = bf2f((unsigned short)(u1 & 0xffff)), d1 = bf2f((unsigned short)(u1 >> 16));
            float x0 = bf2f((unsigned short)(u0 & 0xffff)), d0 = bf2f((unsigned short)(u0 >> 16));
            float B3 = Bp[(j+3)*DS];
            float B2 = Bp[(j+2)*DS];
            float B1 = Bp[(j+1)*DS];
            float B0 = Bp[(j+0)*DS];
            float e;
            e = __expf(a * S_run); H = fmaf(e * d3 * x3, B3, H); S_run += d3;
            e = __expf(a * S_run); H = fmaf(e * d2 * x2, B2, H); S_run += d2;
            e = __expf(a * S_run); H = fmaf(e * d1 * x1, B1, H); S_run += d1;
            e = __expf(a * S_run); H = fmaf(e * d0 * x0, B0, H); S_run += d0;
            if (__all(a * S_run < THR)) break;
        }
    }
    if (H != 0.f)
        atomicAdd(hlast + (((size_t)b * DS + s) * DI + d), H);
}

// ---------------------------------------------------------------- K4: the t = L-1 tail
__global__ __launch_bounds__(256) void k4_final(
    const float* __restrict__ z, const float* __restrict__ emb_w,
    const float* __restrict__ emb_b, const float* __restrict__ in_proj_w,
    const float* __restrict__ conv_w, const float* __restrict__ conv_b,
    const float* __restrict__ x_proj_w, const float* __restrict__ D_skip,
    const float* __restrict__ out_proj_w, const float* __restrict__ norm_w,
    const float* __restrict__ norm_b, const float* __restrict__ cls_w,
    const float* __restrict__ cls_b, const float* __restrict__ W1,
    const float* __restrict__ b1, const float* __restrict__ h_last,
    float* __restrict__ out)
{
    __shared__ float zl[4][64];
    __shared__ float xlast[DI];
    __shared__ float xemb[DM];
    __shared__ float Cl[DS];
    __shared__ float ylds[DI];
    __shared__ float olds[DM];
    int b = blockIdx.x, tid = threadIdx.x;
    {
        int r = tid >> 6, k = tid & 63;
        zl[r][k] = z[((size_t)b * L_ + (L_ - 4 + r)) * LAT + k];
    }
    __syncthreads();
    {   // x at t = L-1 (conv over last 4 x_pre)
        int d = tid;
        const float* wr = W1 + d * LAT;
        float xp[4];
        #pragma unroll
        for (int r = 0; r < 4; ++r) {
            float acc = b1[d];
            for (int k = 0; k < LAT; ++k) acc += zl[r][k] * wr[k];
            xp[r] = acc;
        }
        float4 cwv = *(const float4*)(conv_w + d * 4);
        float xc = cwv.x*xp[0] + cwv.y*xp[1] + cwv.z*xp[2] + cwv.w*xp[3] + conv_b[d];
        xlast[d] = siluf(xc);
    }
    __syncthreads();
    if (tid < DS) {   // C at L-1
        float acc = 0.f;
        const float* wr = x_proj_w + (size_t)(DR + DS + tid) * DI;
        for (int k = 0; k < DI; ++k) acc += xlast[k] * wr[k];
        Cl[tid] = acc;
    }
    if (tid >= 64 && tid < 64 + DM) {   // x_emb at L-1 (for z-branch)
        int m = tid - 64;
        float acc = emb_b[m];
        const float* wr = emb_w + (size_t)m * LAT;
        for (int k = 0; k < LAT; ++k) acc += zl[3][k] * wr[k];
        xemb[m] = acc;
    }
    __syncthreads();
    {   // y = (h.C) + x*D_skip, gated by silu(z-branch)
        int d = tid;
        float hs = 0.f;
        #pragma unroll
        for (int si = 0; si < DS; ++si)
            hs += h_last[((size_t)b * DS + si) * DI + d] * Cl[si];
        float y = hs + xlast[d] * D_skip[d];
        float zbv = 0.f;
        const float* wr = in_proj_w + (size_t)(DI + d) * DM;
        for (int m = 0; m < DM; ++m) zbv += xemb[m] * wr[m];
        y *= siluf(zbv);
        ylds[d] = y;
    }
    __syncthreads();
    if (tid < DM) {   // out_proj
        float acc = 0.f;
        const float* wr = out_proj_w + (size_t)tid * DI;
        for (int k = 0; k < DI; ++k) acc += ylds[k] * wr[k];
        olds[tid] = acc;
    }
    __syncthreads();
    if (tid < 64) {   // LayerNorm + classifier (one wave)
        float v0 = olds[tid], v1 = olds[tid + 64];
        float sum = v0 + v1;
        #pragma unroll
        for (int off = 32; off > 0; off >>= 1) sum += __shfl_down(sum, off);
        float mu = __shfl(sum, 0) * (1.0f / 128.0f);
        float dv0 = v0 - mu, dv1 = v1 - mu;
        float vs = dv0 * dv0 + dv1 * dv1;
        #pragma unroll
        for (int off = 32; off > 0; off >>= 1) vs += __shfl_down(vs, off);
        float var = __shfl(vs, 0) * (1.0f / 128.0f);
        float rstd = rsqrtf(var + 1e-5f);
        float xn0 = dv0 * rstd * norm_w[tid] + norm_b[tid];
        float xn1 = dv1 * rstd * norm_w[tid + 64] + norm_b[tid + 64];
        float lg = xn0 * cls_w[tid] + xn1 * cls_w[tid + 64];
        #pragma unroll
        for (int off = 32; off > 0; off >>= 1) lg += __shfl_down(lg, off);
        if (tid == 0) out[b] = lg + cls_b[0];
    }
}

// ---------------------------------------------------------------- launch
extern "C" void kernel_launch(void* const* d_in, const int* in_sizes, int n_in,
                              void* d_out, int out_size, void* d_ws, size_t ws_size,
                              hipStream_t stream) {
    (void)in_sizes; (void)n_in; (void)out_size;
    const float* z         = (const float*)d_in[0];
    const float* emb_w     = (const float*)d_in[1];
    const float* emb_b     = (const float*)d_in[2];
    const float* in_proj_w = (const float*)d_in[3];
    const float* conv_w    = (const float*)d_in[4];
    const float* conv_b    = (const float*)d_in[5];
    const float* x_proj_w  = (const float*)d_in[6];
    const float* dt_proj_w = (const float*)d_in[7];
    const float* dt_proj_b = (const float*)d_in[8];
    const float* A_log     = (const float*)d_in[9];
    const float* D_skip    = (const float*)d_in[10];
    const float* out_proj_w= (const float*)d_in[11];
    const float* norm_w    = (const float*)d_in[12];
    const float* norm_b    = (const float*)d_in[13];
    const float* cls_w     = (const float*)d_in[14];
    const float* cls_b     = (const float*)d_in[15];
    float* out = (float*)d_out;

    float* ws    = (float*)d_ws;
    float* W1    = ws;                       // 16384 f
    float* b1    = W1 + 16384;               // 256 f
    float* Bssm  = b1 + 256;                 // 16*3600*16  = 921600 f
    float* Dcs   = Bssm + 921600;            // 16*80*256   = 327680 f
    float* Rsuf  = Dcs + 327680;             // 327680 f (unused; layout kept)
    float* hlast = Rsuf + 327680;            // 16*16*256   = 65536 f
    float* fend  = hlast + 65536;
    unsigned short* W1h  = (unsigned short*)fend;             // 16384 u16
    unsigned short* W1l  = W1h + 16384;                       // 16384 u16
    unsigned short* xwh  = W1l + 16384;                       // 24*256 = 6144 u16
    unsigned short* xwl  = xwh + 6144;                        // 6144 u16
    unsigned int*   xd   = (unsigned int*)(xwl + 6144);       // 16*3600*256 u32 (x lo, dt hi)
    size_t needed = ((size_t)(16384 + 256 + 921600 + 327680 + 327680 + 65536)) * 4
                  + ((size_t)(16384 + 16384 + 6144 + 6144)) * 2
                  + (size_t)B_ * L_ * DI * 4;
    if (ws_size < needed) return;

    k0_combine <<<dim3(DI + 24),     dim3(LAT), 0, stream>>>(in_proj_w, emb_w, emb_b, x_proj_w,
                                                             W1, b1, W1h, W1l, xwh, xwl);
    k1_front   <<<dim3(NT, B_),      dim3(256), 0, stream>>>(z, conv_w, conv_b, dt_proj_w, dt_proj_b,
                                                             W1h, W1l, xwh, xwl, b1,
                                                             Bssm, Dcs, xd, hlast);
    k3b_scan   <<<dim3(NC, 8, B_),   dim3(512), 0, stream>>>(xd, Bssm, A_log, Dcs, hlast);
    k4_final   <<<dim3(B_),          dim3(256), 0, stream>>>(z, emb_w, emb_b, in_proj_w, conv_w, conv_b,
                                                             x_proj_w, D_skip, out_proj_w, norm_w, norm_b,
                                                             cls_w, cls_b, W1, b1, hlast, out);
}

// Round 8
// 128.648 us; speedup vs baseline: 1.8655x; 1.8655x over previous
//
#include <hip/hip_runtime.h>
#include <hip/hip_bf16.h>
#include <math.h>

#define B_  16
#define L_  3600
#define LAT 64
#define DM  128
#define DI  256
#define DS  16
#define DR  8

#define TT  45    // K1 time-tile == scan chunk length
#define NT  80    // 3600/45 tiles == chunks
#define NC  80
#define TC  45
#define THR (-20.0f)   // exp(a*S) < exp(-20) ~ 2e-9 -> negligible

typedef __bf16 v8bf __attribute__((ext_vector_type(8)));
typedef float  v4f  __attribute__((ext_vector_type(4)));
typedef unsigned short v8us __attribute__((ext_vector_type(8)));

#define MFMA16(A, Bf, C) __builtin_amdgcn_mfma_f32_16x16x32_bf16((A), (Bf), (C), 0, 0, 0)

__device__ __forceinline__ float siluf(float v) {
    return v * __builtin_amdgcn_rcpf(1.0f + __expf(-v));
}
__device__ __forceinline__ float softplusf(float v) {
    float r = __logf(1.0f + __expf(v));
    return (v > 15.0f) ? v : r;
}
__device__ __forceinline__ float bf2f(unsigned short u) {
    unsigned int x = ((unsigned int)u) << 16;
    return __builtin_bit_cast(float, x);
}
__device__ __forceinline__ unsigned short f2bf(float f) {
    __hip_bfloat16 h = __float2bfloat16(f);
    return __builtin_bit_cast(unsigned short, h);
}

// ---------------------------------------------------------------- K0: W1 = in_proj_x @ emb_w (+ hi/lo bf16), b1; pre-swizzled x_proj hi/lo
__global__ __launch_bounds__(64) void k0_combine(
    const float* __restrict__ in_proj_w, const float* __restrict__ emb_w,
    const float* __restrict__ emb_b, const float* __restrict__ x_proj_w,
    float* __restrict__ W1, float* __restrict__ b1,
    unsigned short* __restrict__ W1h, unsigned short* __restrict__ W1l,
    unsigned short* __restrict__ xwh, unsigned short* __restrict__ xwl)
{
    int blk = blockIdx.x, k = threadIdx.x;
    if (blk < DI) {
        int d = blk;
        const float* row = in_proj_w + (size_t)d * DM;
        float acc = 0.f;
        for (int m = 0; m < DM; ++m) acc += row[m] * emb_w[m * LAT + k];
        W1[d * LAT + k] = acc;
        unsigned short h = f2bf(acc);
        W1h[d * LAT + k] = h;
        W1l[d * LAT + k] = f2bf(acc - bf2f(h));
        if (k == 0) {
            float ab = 0.f;
            for (int m = 0; m < DM; ++m) ab += row[m] * emb_b[m];
            b1[d] = ab;
        }
    } else {
        int j = blk - DI;   // 0..23
        int sw = (j & 7) << 3;
        #pragma unroll
        for (int q = 0; q < 4; ++q) {
            int c = k * 4 + q;
            float v = x_proj_w[(size_t)j * DI + c];
            unsigned short h = f2bf(v);
            int idx = j * 256 + (c ^ sw);
            xwh[idx] = h;
            xwl[idx] = f2bf(v - bf2f(h));
        }
    }
}

// ---------------------------------------------------------------- K1: MFMA front-end + dt + chunk dt-sums
// 1 tile/block, 1280 blocks; LDS 33,056 B, launch_bounds(256,4) -> 4 blocks/CU
// (VGPR cap 128, no spill), 1.25 dispatch rounds.
// LDS byte map (smem region):
//   phase A/conv : [0,16448) xpre f32[16][257] | [16448,22592) z-hi | [22592,28736) z-lo
//   phase B      : [0,24576) xt16 u16[48][256] swz (xw frags read from GLOBAL, L2-hot)
// Bssm staged in bl[45][16] LDS, written coalesced in phase C (kills 16x write-amp).
__global__ __launch_bounds__(256, 4) void k1_front(
    const float* __restrict__ z, const float* __restrict__ conv_w,
    const float* __restrict__ conv_b, const float* __restrict__ dt_proj_w,
    const float* __restrict__ dt_proj_b,
    const unsigned short* __restrict__ W1h, const unsigned short* __restrict__ W1l,
    const unsigned short* __restrict__ xwh, const unsigned short* __restrict__ xwl,
    const float* __restrict__ b1,
    float* __restrict__ Bssm, float* __restrict__ Dcs,
    unsigned int* __restrict__ xd, float* __restrict__ hlast)
{
    __shared__ __align__(16) unsigned char smem[28736];
    __shared__ float dtl[TT][8];
    __shared__ float bl[TT][DS];
    float* xpre = (float*)smem;                              // [16][257] f32
    unsigned short* zth = (unsigned short*)(smem + 16448);   // 3072 u16
    unsigned short* ztl = (unsigned short*)(smem + 22592);   // 3072 u16
    unsigned short* xt16 = (unsigned short*)smem;            // [48][256] swz

    int b = blockIdx.y, tile = blockIdx.x;
    int t0 = tile * TT;
    int t0m3 = t0 - 3;
    int tid = threadIdx.x;
    int lane = tid & 63, wid = tid >> 6;
    int l15 = lane & 15, l4 = lane >> 4;

    // zero hlast (poisoned workspace) -- before k3b runs
    if (tile == 0) {
        float4 z4 = make_float4(0.f, 0.f, 0.f, 0.f);
        float4* hl4 = (float4*)(hlast + (size_t)b * (DS * DI));
        #pragma unroll
        for (int i = 0; i < 4; ++i) hl4[tid + i * 256] = z4;
    }

    // per-thread conv + dt params (channel d = tid)
    float4 cw = *(const float4*)(conv_w + tid * 4);
    float cb = conv_b[tid];
    float bias = b1[tid];
    float4 dwA = *(const float4*)(dt_proj_w + (size_t)tid * DR);
    float4 dwB = *(const float4*)(dt_proj_w + (size_t)tid * DR + 4);
    float dbias = dt_proj_b[tid];

    // ---- B-frags for phase A from W1 hi/lo (once per block)
    v8bf wh[4][2], wl[4][2];
    int d0w = wid * 64;
    {
        #pragma unroll
        for (int nt = 0; nt < 4; ++nt) {
            int dr = d0w + nt * 16 + l15;
            #pragma unroll
            for (int kb = 0; kb < 2; ++kb) {
                int k0 = kb * 32 + l4 * 8;
                wh[nt][kb] = __builtin_bit_cast(v8bf, *(const v8us*)(W1h + (size_t)dr * LAT + k0));
                wl[nt][kb] = __builtin_bit_cast(v8bf, *(const v8us*)(W1l + (size_t)dr * LAT + k0));
            }
        }
    }

    // ---- stage z tile (48 rows incl history) as hi/lo bf16, XOR-swizzled rows
    {
        const float* zb = z + (size_t)b * L_ * LAT;
        for (int i = tid; i < 48 * 8; i += 256) {   // (row, 8-elem slot)
            int r = i >> 3, s = i & 7;
            int tg = t0m3 + r;
            float f[8];
            if (tg >= 0) {
                float4 u = *(const float4*)(zb + (size_t)tg * LAT + s * 8);
                float4 v = *(const float4*)(zb + (size_t)tg * LAT + s * 8 + 4);
                f[0]=u.x; f[1]=u.y; f[2]=u.z; f[3]=u.w; f[4]=v.x; f[5]=v.y; f[6]=v.z; f[7]=v.w;
            } else {
                #pragma unroll
                for (int q = 0; q < 8; ++q) f[q] = 0.f;
            }
            v8us hh, ll;
            #pragma unroll
            for (int q = 0; q < 8; ++q) {
                unsigned short h = f2bf(f[q]);
                hh[q] = h;
                ll[q] = f2bf(f[q] - bf2f(h));
            }
            int idx = r * 64 + ((s * 8) ^ ((r & 7) << 3));   // u16 units, 16B slots
            *(v8us*)&zth[idx] = hh;
            *(v8us*)&ztl[idx] = ll;
        }
    }
    __syncthreads();

    float xr[TT];
    float p0 = 0.f, p1 = 0.f, p2 = 0.f;

    // ---- phase A in 3 sub-phases of 16 rows: MFMA(mt) -> bar -> conv -> bar
    #pragma unroll
    for (int mt = 0; mt < 3; ++mt) {
        {   // MFMA m-tile mt (writes xpre rows 0..15)
            int r = mt * 16 + l15;
            int sw = (r & 7) << 3;
            int kb0 = l4 * 8;
            v8bf ah0 = __builtin_bit_cast(v8bf, *(const v8us*)&zth[r * 64 + (kb0 ^ sw)]);
            v8bf ah1 = __builtin_bit_cast(v8bf, *(const v8us*)&zth[r * 64 + ((32 + kb0) ^ sw)]);
            v8bf al0 = __builtin_bit_cast(v8bf, *(const v8us*)&ztl[r * 64 + (kb0 ^ sw)]);
            v8bf al1 = __builtin_bit_cast(v8bf, *(const v8us*)&ztl[r * 64 + ((32 + kb0) ^ sw)]);
            int rr = l4 * 4;
            #pragma unroll
            for (int nt = 0; nt < 4; ++nt) {
                v4f acc = {0.f, 0.f, 0.f, 0.f};
                acc = MFMA16(ah0, wh[nt][0], acc);
                acc = MFMA16(ah1, wh[nt][1], acc);
                acc = MFMA16(ah0, wl[nt][0], acc);
                acc = MFMA16(ah1, wl[nt][1], acc);
                acc = MFMA16(al0, wh[nt][0], acc);
                acc = MFMA16(al1, wh[nt][1], acc);
                int cc = d0w + nt * 16 + l15;
                xpre[(rr + 0) * 257 + cc] = acc[0];
                xpre[(rr + 1) * 257 + cc] = acc[1];
                xpre[(rr + 2) * 257 + cc] = acc[2];
                xpre[(rr + 3) * 257 + cc] = acc[3];
            }
        }
        __syncthreads();
        {   // conv rows mt*16 .. mt*16+15
            int d = tid;
            if (mt == 0) {
                p0 = xpre[0 * 257 + d] + ((t0m3 + 0 >= 0) ? bias : 0.f);
                p1 = xpre[1 * 257 + d] + ((t0m3 + 1 >= 0) ? bias : 0.f);
                p2 = xpre[2 * 257 + d] + ((t0m3 + 2 >= 0) ? bias : 0.f);
                #pragma unroll
                for (int r = 3; r < 16; ++r) {
                    float cur = xpre[r * 257 + d] + bias;
                    float xc = cw.x * p0 + cw.y * p1 + cw.z * p2 + cw.w * cur + cb;
                    xr[r - 3] = siluf(xc);
                    p0 = p1; p1 = p2; p2 = cur;
                }
            } else {
                int rbase = mt * 16;
                #pragma unroll
                for (int q = 0; q < 16; ++q) {
                    float cur = xpre[q * 257 + d] + bias;
                    float xc = cw.x * p0 + cw.y * p1 + cw.z * p2 + cw.w * cur + cb;
                    xr[rbase + q - 3] = siluf(xc);
                    p0 = p1; p1 = p2; p2 = cur;
                }
            }
        }
        __syncthreads();
    }

    // ---- write xt bf16 (swizzled; xpre & z-tile now dead)
    {
        int d = tid;
        #pragma unroll
        for (int t = 0; t < TT; ++t)
            xt16[t * 256 + (d ^ ((t & 7) << 3))] = f2bf(xr[t]);
        #pragma unroll
        for (int t = TT; t < 48; ++t)
            xt16[t * 256 + (d ^ ((t & 7) << 3))] = 0;
    }
    __syncthreads();

    // ---- phase B MFMA: x_dbl[t][j] = sum_k xt[t][k] * x_proj_w[j][k], j = 0..23
    //      B-frags (xw hi/lo) read directly from GLOBAL (pre-swizzled by k0; 24 KB, L2-hot)
    if (wid < 3) {
        int mt = wid;
        int rA = mt * 16 + l15;
        int swA = (rA & 7) << 3;
        int jc0 = l15;
        int jc1 = 16 + l15; if (jc1 > 23) jc1 = 23;   // clamp (outputs >=24 discarded)
        v4f acc0 = {0.f, 0.f, 0.f, 0.f}, acc1 = {0.f, 0.f, 0.f, 0.f};
        #pragma unroll
        for (int kb = 0; kb < 8; ++kb) {
            int k0 = kb * 32 + l4 * 8;
            v8bf xa  = __builtin_bit_cast(v8bf, *(const v8us*)&xt16[rA * 256 + (k0 ^ swA)]);
            int s0 = k0 ^ ((jc0 & 7) << 3);
            int s1 = k0 ^ ((jc1 & 7) << 3);
            v8bf b0h = __builtin_bit_cast(v8bf, *(const v8us*)(xwh + jc0 * 256 + s0));
            v8bf b0l = __builtin_bit_cast(v8bf, *(const v8us*)(xwl + jc0 * 256 + s0));
            v8bf b1h = __builtin_bit_cast(v8bf, *(const v8us*)(xwh + jc1 * 256 + s1));
            v8bf b1l = __builtin_bit_cast(v8bf, *(const v8us*)(xwl + jc1 * 256 + s1));
            acc0 = MFMA16(xa, b0h, acc0);
            acc0 = MFMA16(xa, b0l, acc0);
            acc1 = MFMA16(xa, b1h, acc1);
            acc1 = MFMA16(xa, b1l, acc1);
        }
        int rr = mt * 16 + l4 * 4;
        #pragma unroll
        for (int reg = 0; reg < 4; ++reg) {
            int t = rr + reg;
            if (t < TT) {
                float v0 = acc0[reg], v1 = acc1[reg];
                if (l15 < 8) {
                    dtl[t][l15] = v0;          // dt_in cols 0..7
                    bl[t][8 + l15] = v1;       // B cols 8..15 (j = 16..23)
                } else {
                    bl[t][l15 - 8] = v0;       // B cols 0..7 (j = 8..15)
                }
            }
        }
    }
    __syncthreads();

    // ---- phase C: Bssm coalesced store (from bl) + dt = softplus(...) packed store + per-tile sum
    {
        // coalesced Bssm: 720 consecutive floats, 256B per wave-store
        float* Bout = Bssm + ((size_t)b * L_ + t0) * DS;
        #pragma unroll
        for (int i = tid; i < TT * DS; i += 256)
            Bout[i] = bl[i >> 4][i & 15];

        int d = tid;
        unsigned int* xdout = xd + ((size_t)b * L_ + t0) * DI + d;
        float S = 0.f;
        #pragma unroll 5
        for (int t = 0; t < TT; ++t) {
            float4 u = *(const float4*)&dtl[t][0];
            float4 v = *(const float4*)&dtl[t][4];
            float r = dbias + u.x*dwA.x + u.y*dwA.y + u.z*dwA.z + u.w*dwA.w
                            + v.x*dwB.x + v.y*dwB.y + v.z*dwB.z + v.w*dwB.w;
            float dt = softplusf(r);
            unsigned int pack = ((unsigned int)f2bf(dt) << 16) | (unsigned int)f2bf(xr[t]);
            xdout[(size_t)t * DI] = pack;
            S += dt;
        }
        Dcs[((size_t)b * NC + tile) * DI + d] = S;
    }
}

// ---------------------------------------------------------------- K3a2: suffix sums of chunk dt-sums (register-preloaded, no serial load chain)
__global__ __launch_bounds__(256) void k3a2_suffix(
    const float* __restrict__ Dcs, float* __restrict__ Rsuf)
{
    int b = blockIdx.x, d = threadIdx.x;
    const float* src = Dcs + (size_t)b * NC * DI + d;
    float* dst = Rsuf + (size_t)b * NC * DI + d;
    float v[40];
    float R = 0.f;
    // upper half: c = 79..40
    #pragma unroll
    for (int i = 0; i < 40; ++i) v[i] = src[(size_t)(NC - 1 - i) * DI];
    #pragma unroll
    for (int i = 0; i < 40; ++i) { dst[(size_t)(NC - 1 - i) * DI] = R; R += v[i]; }
    // lower half: c = 39..0
    #pragma unroll
    for (int i = 0; i < 40; ++i) v[i] = src[(size_t)(39 - i) * DI];
    #pragma unroll
    for (int i = 0; i < 40; ++i) { dst[(size_t)(39 - i) * DI] = R; R += v[i]; }
}

// ---------------------------------------------------------------- K3b: streaming suffix reduction; atomic combine into hlast
__global__ __launch_bounds__(512) void k3b_scan(
    const unsigned int* __restrict__ xd,
    const float* __restrict__ Bssm, const float* __restrict__ A_log,
    const float* __restrict__ Rsuf, float* __restrict__ hlast)
{
    int c = blockIdx.x, dg = blockIdx.y, b = blockIdx.z;
    int tid = threadIdx.x;
    int dh = tid & 31;
    int s  = ((tid >> 6) << 1) | ((tid >> 5) & 1);
    int d  = dg * 32 + dh;

    float a = -__expf(A_log[d * DS + s]);
    float R = Rsuf[((size_t)b * NC + c) * DI + d];

    float H = 0.f;
    float S_run = R;
    if (!__all(a * R < THR)) {
        int t0 = c * TC;
        const unsigned int* xp = xd + ((size_t)b * L_ + t0) * DI + d;
        const float* Bp = Bssm + ((size_t)b * L_ + t0) * DS + s;
        {   // t = TT-1 single (45 = 11*4 + 1)
            unsigned int u4 = xp[(TC-1)*DI];
            float x4 = bf2f((unsigned short)(u4 & 0xffff));
            float d4 = bf2f((unsigned short)(u4 >> 16));
            float B4 = Bp[(TC-1)*DS];
            float e = __expf(a * S_run); H = fmaf(e * d4 * x4, B4, H); S_run += d4;
        }
        for (int j = TC - 5; j >= 0; j -= 4) {
            unsigned int u3 = xp[(j+3)*DI];
            unsigned int u2 = xp[(j+2)*DI];
            unsigned int u1 = xp[(j+1)*DI];
            unsigned int u0 = xp[(j+0)*DI];
            float x3 = bf2f((unsigned short)(u3 & 0xffff)), d3 = bf2f((unsigned short)(u3 >> 16));
            float x2 = bf2f((unsigned short)(u2 & 0xffff)), d2 = bf2f((unsigned short)(u2 >> 16));
            float x1 = bf2f((unsigned short)(u1 & 0xffff)), d1 = bf2f((unsigned short)(u1 >> 16));
            float x0 = bf2f((unsigned short)(u0 & 0xffff)), d0 = bf2f((unsigned short)(u0 >> 16));
            float B3 = Bp[(j+3)*DS];
            float B2 = Bp[(j+2)*DS];
            float B1 = Bp[(j+1)*DS];
            float B0 = Bp[(j+0)*DS];
            float e;
            e = __expf(a * S_run); H = fmaf(e * d3 * x3, B3, H); S_run += d3;
            e = __expf(a * S_run); H = fmaf(e * d2 * x2, B2, H); S_run += d2;
            e = __expf(a * S_run); H = fmaf(e * d1 * x1, B1, H); S_run += d1;
            e = __expf(a * S_run); H = fmaf(e * d0 * x0, B0, H); S_run += d0;
            if (__all(a * S_run < THR)) break;
        }
    }
    if (H != 0.f)
        atomicAdd(hlast + (((size_t)b * DS + s) * DI + d), H);
}

// ---------------------------------------------------------------- K4: the t = L-1 tail
__global__ __launch_bounds__(256) void k4_final(
    const float* __restrict__ z, const float* __restrict__ emb_w,
    const float* __restrict__ emb_b, const float* __restrict__ in_proj_w,
    const float* __restrict__ conv_w, const float* __restrict__ conv_b,
    const float* __restrict__ x_proj_w, const float* __restrict__ D_skip,
    const float* __restrict__ out_proj_w, const float* __restrict__ norm_w,
    const float* __restrict__ norm_b, const float* __restrict__ cls_w,
    const float* __restrict__ cls_b, const float* __restrict__ W1,
    const float* __restrict__ b1, const float* __restrict__ h_last,
    float* __restrict__ out)
{
    __shared__ float zl[4][64];
    __shared__ float xlast[DI];
    __shared__ float xemb[DM];
    __shared__ float Cl[DS];
    __shared__ float ylds[DI];
    __shared__ float olds[DM];
    int b = blockIdx.x, tid = threadIdx.x;
    {
        int r = tid >> 6, k = tid & 63;
        zl[r][k] = z[((size_t)b * L_ + (L_ - 4 + r)) * LAT + k];
    }
    __syncthreads();
    {   // x at t = L-1 (conv over last 4 x_pre)
        int d = tid;
        const float* wr = W1 + d * LAT;
        float xp[4];
        #pragma unroll
        for (int r = 0; r < 4; ++r) {
            float acc = b1[d];
            for (int k = 0; k < LAT; ++k) acc += zl[r][k] * wr[k];
            xp[r] = acc;
        }
        float4 cwv = *(const float4*)(conv_w + d * 4);
        float xc = cwv.x*xp[0] + cwv.y*xp[1] + cwv.z*xp[2] + cwv.w*xp[3] + conv_b[d];
        xlast[d] = siluf(xc);
    }
    __syncthreads();
    if (tid < DS) {   // C at L-1
        float acc = 0.f;
        const float* wr = x_proj_w + (size_t)(DR + DS + tid) * DI;
        for (int k = 0; k < DI; ++k) acc += xlast[k] * wr[k];
        Cl[tid] = acc;
    }
    if (tid >= 64 && tid < 64 + DM) {   // x_emb at L-1 (for z-branch)
        int m = tid - 64;
        float acc = emb_b[m];
        const float* wr = emb_w + (size_t)m * LAT;
        for (int k = 0; k < LAT; ++k) acc += zl[3][k] * wr[k];
        xemb[m] = acc;
    }
    __syncthreads();
    {   // y = (h.C) + x*D_skip, gated by silu(z-branch)
        int d = tid;
        float hs = 0.f;
        #pragma unroll
        for (int si = 0; si < DS; ++si)
            hs += h_last[((size_t)b * DS + si) * DI + d] * Cl[si];
        float y = hs + xlast[d] * D_skip[d];
        float zbv = 0.f;
        const float* wr = in_proj_w + (size_t)(DI + d) * DM;
        for (int m = 0; m < DM; ++m) zbv += xemb[m] * wr[m];
        y *= siluf(zbv);
        ylds[d] = y;
    }
    __syncthreads();
    if (tid < DM) {   // out_proj
        float acc = 0.f;
        const float* wr = out_proj_w + (size_t)tid * DI;
        for (int k = 0; k < DI; ++k) acc += ylds[k] * wr[k];
        olds[tid] = acc;
    }
    __syncthreads();
    if (tid < 64) {   // LayerNorm + classifier (one wave)
        float v0 = olds[tid], v1 = olds[tid + 64];
        float sum = v0 + v1;
        #pragma unroll
        for (int off = 32; off > 0; off >>= 1) sum += __shfl_down(sum, off);
        float mu = __shfl(sum, 0) * (1.0f / 128.0f);
        float dv0 = v0 - mu, dv1 = v1 - mu;
        float vs = dv0 * dv0 + dv1 * dv1;
        #pragma unroll
        for (int off = 32; off > 0; off >>= 1) vs += __shfl_down(vs, off);
        float var = __shfl(vs, 0) * (1.0f / 128.0f);
        float rstd = rsqrtf(var + 1e-5f);
        float xn0 = dv0 * rstd * norm_w[tid] + norm_b[tid];
        float xn1 = dv1 * rstd * norm_w[tid + 64] + norm_b[tid + 64];
        float lg = xn0 * cls_w[tid] + xn1 * cls_w[tid + 64];
        #pragma unroll
        for (int off = 32; off > 0; off >>= 1) lg += __shfl_down(lg, off);
        if (tid == 0) out[b] = lg + cls_b[0];
    }
}

// ---------------------------------------------------------------- launch
extern "C" void kernel_launch(void* const* d_in, const int* in_sizes, int n_in,
                              void* d_out, int out_size, void* d_ws, size_t ws_size,
                              hipStream_t stream) {
    (void)in_sizes; (void)n_in; (void)out_size;
    const float* z         = (const float*)d_in[0];
    const float* emb_w     = (const float*)d_in[1];
    const float* emb_b     = (const float*)d_in[2];
    const float* in_proj_w = (const float*)d_in[3];
    const float* conv_w    = (const float*)d_in[4];
    const float* conv_b    = (const float*)d_in[5];
    const float* x_proj_w  = (const float*)d_in[6];
    const float* dt_proj_w = (const float*)d_in[7];
    const float* dt_proj_b = (const float*)d_in[8];
    const float* A_log     = (const float*)d_in[9];
    const float* D_skip    = (const float*)d_in[10];
    const float* out_proj_w= (const float*)d_in[11];
    const float* norm_w    = (const float*)d_in[12];
    const float* norm_b    = (const float*)d_in[13];
    const float* cls_w     = (const float*)d_in[14];
    const float* cls_b     = (const float*)d_in[15];
    float* out = (float*)d_out;

    float* ws    = (float*)d_ws;
    float* W1    = ws;                       // 16384 f
    float* b1    = W1 + 16384;               // 256 f
    float* Bssm  = b1 + 256;                 // 16*3600*16  = 921600 f
    float* Dcs   = Bssm + 921600;            // 16*80*256   = 327680 f
    float* Rsuf  = Dcs + 327680;             // 327680 f
    float* hlast = Rsuf + 327680;            // 16*16*256   = 65536 f
    float* fend  = hlast + 65536;
    unsigned short* W1h  = (unsigned short*)fend;             // 16384 u16
    unsigned short* W1l  = W1h + 16384;                       // 16384 u16
    unsigned short* xwh  = W1l + 16384;                       // 24*256 = 6144 u16
    unsigned short* xwl  = xwh + 6144;                        // 6144 u16
    unsigned int*   xd   = (unsigned int*)(xwl + 6144);       // 16*3600*256 u32 (x lo, dt hi)
    size_t needed = ((size_t)(16384 + 256 + 921600 + 327680 + 327680 + 65536)) * 4
                  + ((size_t)(16384 + 16384 + 6144 + 6144)) * 2
                  + (size_t)B_ * L_ * DI * 4;
    if (ws_size < needed) return;

    k0_combine <<<dim3(DI + 24),     dim3(LAT), 0, stream>>>(in_proj_w, emb_w, emb_b, x_proj_w,
                                                             W1, b1, W1h, W1l, xwh, xwl);
    k1_front   <<<dim3(NT, B_),      dim3(256), 0, stream>>>(z, conv_w, conv_b, dt_proj_w, dt_proj_b,
                                                             W1h, W1l, xwh, xwl, b1,
                                                             Bssm, Dcs, xd, hlast);
    k3a2_suffix<<<dim3(B_),          dim3(256), 0, stream>>>(Dcs, Rsuf);
    k3b_scan   <<<dim3(NC, 8, B_),   dim3(512), 0, stream>>>(xd, Bssm, A_log, Rsuf, hlast);
    k4_final   <<<dim3(B_),          dim3(256), 0, stream>>>(z, emb_w, emb_b, in_proj_w, conv_w, conv_b,
                                                             x_proj_w, D_skip, out_proj_w, norm_w, norm_b,
                                                             cls_w, cls_b, W1, b1, hlast, out);
}

// Round 9
// 116.815 us; speedup vs baseline: 2.0545x; 1.1013x over previous
//
#include <hip/hip_runtime.h>
#include <hip/hip_bf16.h>
#include <math.h>

#define B_  16
#define L_  3600
#define LAT 64
#define DM  128
#define DI  256
#define DS  16
#define DR  8

#define TT  45    // K1 time-tile == scan chunk length
#define NT  80    // 3600/45 tiles == chunks
#define NC  80
#define TC  45
#define THR (-20.0f)   // exp(a*S) < exp(-20) ~ 2e-9 -> negligible

typedef __bf16 v8bf __attribute__((ext_vector_type(8)));
typedef float  v4f  __attribute__((ext_vector_type(4)));
typedef unsigned short v8us __attribute__((ext_vector_type(8)));

#define MFMA16(A, Bf, C) __builtin_amdgcn_mfma_f32_16x16x32_bf16((A), (Bf), (C), 0, 0, 0)

__device__ __forceinline__ float siluf(float v) {
    return v * __builtin_amdgcn_rcpf(1.0f + __expf(-v));
}
__device__ __forceinline__ float softplusf(float v) {
    float r = __logf(1.0f + __expf(v));
    return (v > 15.0f) ? v : r;
}
__device__ __forceinline__ float bf2f(unsigned short u) {
    unsigned int x = ((unsigned int)u) << 16;
    return __builtin_bit_cast(float, x);
}
__device__ __forceinline__ unsigned short f2bf(float f) {
    __hip_bfloat16 h = __float2bfloat16(f);
    return __builtin_bit_cast(unsigned short, h);
}

// ---------------------------------------------------------------- K0: W1 = in_proj_x @ emb_w (+ hi/lo bf16), b1; pre-swizzled x_proj hi/lo
__global__ __launch_bounds__(64) void k0_combine(
    const float* __restrict__ in_proj_w, const float* __restrict__ emb_w,
    const float* __restrict__ emb_b, const float* __restrict__ x_proj_w,
    float* __restrict__ W1, float* __restrict__ b1,
    unsigned short* __restrict__ W1h, unsigned short* __restrict__ W1l,
    unsigned short* __restrict__ xwh, unsigned short* __restrict__ xwl)
{
    int blk = blockIdx.x, k = threadIdx.x;
    if (blk < DI) {
        int d = blk;
        const float* row = in_proj_w + (size_t)d * DM;
        float acc = 0.f;
        for (int m = 0; m < DM; ++m) acc += row[m] * emb_w[m * LAT + k];
        W1[d * LAT + k] = acc;
        unsigned short h = f2bf(acc);
        W1h[d * LAT + k] = h;
        W1l[d * LAT + k] = f2bf(acc - bf2f(h));
        if (k == 0) {
            float ab = 0.f;
            for (int m = 0; m < DM; ++m) ab += row[m] * emb_b[m];
            b1[d] = ab;
        }
    } else {
        int j = blk - DI;   // 0..23
        int sw = (j & 7) << 3;
        #pragma unroll
        for (int q = 0; q < 4; ++q) {
            int c = k * 4 + q;
            float v = x_proj_w[(size_t)j * DI + c];
            unsigned short h = f2bf(v);
            int idx = j * 256 + (c ^ sw);
            xwh[idx] = h;
            xwl[idx] = f2bf(v - bf2f(h));
        }
    }
}

// ---------------------------------------------------------------- K1: MFMA front-end + dt + chunk dt-sums
// 1 tile/block, 1280 blocks; LDS 33,280 B.
// __launch_bounds__(256,3): empirically the compiler allocates ~84 VGPR (NO
// spill) at arg 3; arg 4 forced 64 VGPR -> 174 MB scratch traffic (round 8),
// arg 5 forced 48 -> worse (round 6). Residency is LDS-bound anyway:
// 4 x 33 KB = 133 KB <= 160 KB and 84 VGPR <= 128 allows 4 waves/SIMD,
// so 4 blocks/CU co-reside WITHOUT declaring it.
// LDS byte map (smem region):
//   phase A/conv : [0,16448) xpre f32[16][257] | [16448,22592) z-hi | [22592,28736) z-lo
//   phase B      : [0,24576) xt16 u16[48][256] swz (xw frags read from GLOBAL, L2-hot)
// Bssm staged in bl[45][16] LDS, written coalesced in phase C (kills 16x write-amp).
__global__ __launch_bounds__(256, 3) void k1_front(
    const float* __restrict__ z, const float* __restrict__ conv_w,
    const float* __restrict__ conv_b, const float* __restrict__ dt_proj_w,
    const float* __restrict__ dt_proj_b,
    const unsigned short* __restrict__ W1h, const unsigned short* __restrict__ W1l,
    const unsigned short* __restrict__ xwh, const unsigned short* __restrict__ xwl,
    const float* __restrict__ b1,
    float* __restrict__ Bssm, float* __restrict__ Dcs,
    unsigned int* __restrict__ xd, float* __restrict__ hlast)
{
    __shared__ __align__(16) unsigned char smem[28736];
    __shared__ float dtl[TT][8];
    __shared__ float bl[TT][DS];
    float* xpre = (float*)smem;                              // [16][257] f32
    unsigned short* zth = (unsigned short*)(smem + 16448);   // 3072 u16
    unsigned short* ztl = (unsigned short*)(smem + 22592);   // 3072 u16
    unsigned short* xt16 = (unsigned short*)smem;            // [48][256] swz

    int b = blockIdx.y, tile = blockIdx.x;
    int t0 = tile * TT;
    int t0m3 = t0 - 3;
    int tid = threadIdx.x;
    int lane = tid & 63, wid = tid >> 6;
    int l15 = lane & 15, l4 = lane >> 4;

    // zero hlast (poisoned workspace) -- before k3b runs
    if (tile == 0) {
        float4 z4 = make_float4(0.f, 0.f, 0.f, 0.f);
        float4* hl4 = (float4*)(hlast + (size_t)b * (DS * DI));
        #pragma unroll
        for (int i = 0; i < 4; ++i) hl4[tid + i * 256] = z4;
    }

    // per-thread conv + dt params (channel d = tid)
    float4 cw = *(const float4*)(conv_w + tid * 4);
    float cb = conv_b[tid];
    float bias = b1[tid];
    float4 dwA = *(const float4*)(dt_proj_w + (size_t)tid * DR);
    float4 dwB = *(const float4*)(dt_proj_w + (size_t)tid * DR + 4);
    float dbias = dt_proj_b[tid];

    // ---- B-frags for phase A from W1 hi/lo (once per block)
    v8bf wh[4][2], wl[4][2];
    int d0w = wid * 64;
    {
        #pragma unroll
        for (int nt = 0; nt < 4; ++nt) {
            int dr = d0w + nt * 16 + l15;
            #pragma unroll
            for (int kb = 0; kb < 2; ++kb) {
                int k0 = kb * 32 + l4 * 8;
                wh[nt][kb] = __builtin_bit_cast(v8bf, *(const v8us*)(W1h + (size_t)dr * LAT + k0));
                wl[nt][kb] = __builtin_bit_cast(v8bf, *(const v8us*)(W1l + (size_t)dr * LAT + k0));
            }
        }
    }

    // ---- stage z tile (48 rows incl history) as hi/lo bf16, XOR-swizzled rows
    {
        const float* zb = z + (size_t)b * L_ * LAT;
        for (int i = tid; i < 48 * 8; i += 256) {   // (row, 8-elem slot)
            int r = i >> 3, s = i & 7;
            int tg = t0m3 + r;
            float f[8];
            if (tg >= 0) {
                float4 u = *(const float4*)(zb + (size_t)tg * LAT + s * 8);
                float4 v = *(const float4*)(zb + (size_t)tg * LAT + s * 8 + 4);
                f[0]=u.x; f[1]=u.y; f[2]=u.z; f[3]=u.w; f[4]=v.x; f[5]=v.y; f[6]=v.z; f[7]=v.w;
            } else {
                #pragma unroll
                for (int q = 0; q < 8; ++q) f[q] = 0.f;
            }
            v8us hh, ll;
            #pragma unroll
            for (int q = 0; q < 8; ++q) {
                unsigned short h = f2bf(f[q]);
                hh[q] = h;
                ll[q] = f2bf(f[q] - bf2f(h));
            }
            int idx = r * 64 + ((s * 8) ^ ((r & 7) << 3));   // u16 units, 16B slots
            *(v8us*)&zth[idx] = hh;
            *(v8us*)&ztl[idx] = ll;
        }
    }
    __syncthreads();

    float xr[TT];
    float p0 = 0.f, p1 = 0.f, p2 = 0.f;

    // ---- phase A in 3 sub-phases of 16 rows: MFMA(mt) -> bar -> conv -> bar
    #pragma unroll
    for (int mt = 0; mt < 3; ++mt) {
        {   // MFMA m-tile mt (writes xpre rows 0..15)
            int r = mt * 16 + l15;
            int sw = (r & 7) << 3;
            int kb0 = l4 * 8;
            v8bf ah0 = __builtin_bit_cast(v8bf, *(const v8us*)&zth[r * 64 + (kb0 ^ sw)]);
            v8bf ah1 = __builtin_bit_cast(v8bf, *(const v8us*)&zth[r * 64 + ((32 + kb0) ^ sw)]);
            v8bf al0 = __builtin_bit_cast(v8bf, *(const v8us*)&ztl[r * 64 + (kb0 ^ sw)]);
            v8bf al1 = __builtin_bit_cast(v8bf, *(const v8us*)&ztl[r * 64 + ((32 + kb0) ^ sw)]);
            int rr = l4 * 4;
            #pragma unroll
            for (int nt = 0; nt < 4; ++nt) {
                v4f acc = {0.f, 0.f, 0.f, 0.f};
                acc = MFMA16(ah0, wh[nt][0], acc);
                acc = MFMA16(ah1, wh[nt][1], acc);
                acc = MFMA16(ah0, wl[nt][0], acc);
                acc = MFMA16(ah1, wl[nt][1], acc);
                acc = MFMA16(al0, wh[nt][0], acc);
                acc = MFMA16(al1, wh[nt][1], acc);
                int cc = d0w + nt * 16 + l15;
                xpre[(rr + 0) * 257 + cc] = acc[0];
                xpre[(rr + 1) * 257 + cc] = acc[1];
                xpre[(rr + 2) * 257 + cc] = acc[2];
                xpre[(rr + 3) * 257 + cc] = acc[3];
            }
        }
        __syncthreads();
        {   // conv rows mt*16 .. mt*16+15
            int d = tid;
            if (mt == 0) {
                p0 = xpre[0 * 257 + d] + ((t0m3 + 0 >= 0) ? bias : 0.f);
                p1 = xpre[1 * 257 + d] + ((t0m3 + 1 >= 0) ? bias : 0.f);
                p2 = xpre[2 * 257 + d] + ((t0m3 + 2 >= 0) ? bias : 0.f);
                #pragma unroll
                for (int r = 3; r < 16; ++r) {
                    float cur = xpre[r * 257 + d] + bias;
                    float xc = cw.x * p0 + cw.y * p1 + cw.z * p2 + cw.w * cur + cb;
                    xr[r - 3] = siluf(xc);
                    p0 = p1; p1 = p2; p2 = cur;
                }
            } else {
                int rbase = mt * 16;
                #pragma unroll
                for (int q = 0; q < 16; ++q) {
                    float cur = xpre[q * 257 + d] + bias;
                    float xc = cw.x * p0 + cw.y * p1 + cw.z * p2 + cw.w * cur + cb;
                    xr[rbase + q - 3] = siluf(xc);
                    p0 = p1; p1 = p2; p2 = cur;
                }
            }
        }
        __syncthreads();
    }

    // ---- write xt bf16 (swizzled; xpre & z-tile now dead)
    {
        int d = tid;
        #pragma unroll
        for (int t = 0; t < TT; ++t)
            xt16[t * 256 + (d ^ ((t & 7) << 3))] = f2bf(xr[t]);
        #pragma unroll
        for (int t = TT; t < 48; ++t)
            xt16[t * 256 + (d ^ ((t & 7) << 3))] = 0;
    }
    __syncthreads();

    // ---- phase B MFMA: x_dbl[t][j] = sum_k xt[t][k] * x_proj_w[j][k], j = 0..23
    //      B-frags (xw hi/lo) read directly from GLOBAL (pre-swizzled by k0; 24 KB, L2-hot)
    if (wid < 3) {
        int mt = wid;
        int rA = mt * 16 + l15;
        int swA = (rA & 7) << 3;
        int jc0 = l15;
        int jc1 = 16 + l15; if (jc1 > 23) jc1 = 23;   // clamp (outputs >=24 discarded)
        v4f acc0 = {0.f, 0.f, 0.f, 0.f}, acc1 = {0.f, 0.f, 0.f, 0.f};
        #pragma unroll
        for (int kb = 0; kb < 8; ++kb) {
            int k0 = kb * 32 + l4 * 8;
            v8bf xa  = __builtin_bit_cast(v8bf, *(const v8us*)&xt16[rA * 256 + (k0 ^ swA)]);
            int s0 = k0 ^ ((jc0 & 7) << 3);
            int s1 = k0 ^ ((jc1 & 7) << 3);
            v8bf b0h = __builtin_bit_cast(v8bf, *(const v8us*)(xwh + jc0 * 256 + s0));
            v8bf b0l = __builtin_bit_cast(v8bf, *(const v8us*)(xwl + jc0 * 256 + s0));
            v8bf b1h = __builtin_bit_cast(v8bf, *(const v8us*)(xwh + jc1 * 256 + s1));
            v8bf b1l = __builtin_bit_cast(v8bf, *(const v8us*)(xwl + jc1 * 256 + s1));
            acc0 = MFMA16(xa, b0h, acc0);
            acc0 = MFMA16(xa, b0l, acc0);
            acc1 = MFMA16(xa, b1h, acc1);
            acc1 = MFMA16(xa, b1l, acc1);
        }
        int rr = mt * 16 + l4 * 4;
        #pragma unroll
        for (int reg = 0; reg < 4; ++reg) {
            int t = rr + reg;
            if (t < TT) {
                float v0 = acc0[reg], v1 = acc1[reg];
                if (l15 < 8) {
                    dtl[t][l15] = v0;          // dt_in cols 0..7
                    bl[t][8 + l15] = v1;       // B cols 8..15 (j = 16..23)
                } else {
                    bl[t][l15 - 8] = v0;       // B cols 0..7 (j = 8..15)
                }
            }
        }
    }
    __syncthreads();

    // ---- phase C: Bssm coalesced store (from bl) + dt = softplus(...) packed store + per-tile sum
    {
        // coalesced Bssm: 720 consecutive floats, 256B per wave-store
        float* Bout = Bssm + ((size_t)b * L_ + t0) * DS;
        #pragma unroll
        for (int i = tid; i < TT * DS; i += 256)
            Bout[i] = bl[i >> 4][i & 15];

        int d = tid;
        unsigned int* xdout = xd + ((size_t)b * L_ + t0) * DI + d;
        float S = 0.f;
        #pragma unroll 5
        for (int t = 0; t < TT; ++t) {
            float4 u = *(const float4*)&dtl[t][0];
            float4 v = *(const float4*)&dtl[t][4];
            float r = dbias + u.x*dwA.x + u.y*dwA.y + u.z*dwA.z + u.w*dwA.w
                            + v.x*dwB.x + v.y*dwB.y + v.z*dwB.z + v.w*dwB.w;
            float dt = softplusf(r);
            unsigned int pack = ((unsigned int)f2bf(dt) << 16) | (unsigned int)f2bf(xr[t]);
            xdout[(size_t)t * DI] = pack;
            S += dt;
        }
        Dcs[((size_t)b * NC + tile) * DI + d] = S;
    }
}

// ---------------------------------------------------------------- K3a2: suffix sums of chunk dt-sums (register-preloaded, no serial load chain)
__global__ __launch_bounds__(256) void k3a2_suffix(
    const float* __restrict__ Dcs, float* __restrict__ Rsuf)
{
    int b = blockIdx.x, d = threadIdx.x;
    const float* src = Dcs + (size_t)b * NC * DI + d;
    float* dst = Rsuf + (size_t)b * NC * DI + d;
    float v[40];
    float R = 0.f;
    // upper half: c = 79..40
    #pragma unroll
    for (int i = 0; i < 40; ++i) v[i] = src[(size_t)(NC - 1 - i) * DI];
    #pragma unroll
    for (int i = 0; i < 40; ++i) { dst[(size_t)(NC - 1 - i) * DI] = R; R += v[i]; }
    // lower half: c = 39..0
    #pragma unroll
    for (int i = 0; i < 40; ++i) v[i] = src[(size_t)(39 - i) * DI];
    #pragma unroll
    for (int i = 0; i < 40; ++i) { dst[(size_t)(39 - i) * DI] = R; R += v[i]; }
}

// ---------------------------------------------------------------- K3b: streaming suffix reduction; atomic combine into hlast
__global__ __launch_bounds__(512) void k3b_scan(
    const unsigned int* __restrict__ xd,
    const float* __restrict__ Bssm, const float* __restrict__ A_log,
    const float* __restrict__ Rsuf, float* __restrict__ hlast)
{
    int c = blockIdx.x, dg = blockIdx.y, b = blockIdx.z;
    int tid = threadIdx.x;
    int dh = tid & 31;
    int s  = ((tid >> 6) << 1) | ((tid >> 5) & 1);
    int d  = dg * 32 + dh;

    float a = -__expf(A_log[d * DS + s]);
    float R = Rsuf[((size_t)b * NC + c) * DI + d];

    float H = 0.f;
    float S_run = R;
    if (!__all(a * R < THR)) {
        int t0 = c * TC;
        const unsigned int* xp = xd + ((size_t)b * L_ + t0) * DI + d;
        const float* Bp = Bssm + ((size_t)b * L_ + t0) * DS + s;
        {   // t = TT-1 single (45 = 11*4 + 1)
            unsigned int u4 = xp[(TC-1)*DI];
            float x4 = bf2f((unsigned short)(u4 & 0xffff));
            float d4 = bf2f((unsigned short)(u4 >> 16));
            float B4 = Bp[(TC-1)*DS];
            float e = __expf(a * S_run); H = fmaf(e * d4 * x4, B4, H); S_run += d4;
        }
        for (int j = TC - 5; j >= 0; j -= 4) {
            unsigned int u3 = xp[(j+3)*DI];
            unsigned int u2 = xp[(j+2)*DI];
            unsigned int u1 = xp[(j+1)*DI];
            unsigned int u0 = xp[(j+0)*DI];
            float x3 = bf2f((unsigned short)(u3 & 0xffff)), d3 = bf2f((unsigned short)(u3 >> 16));
            float x2 = bf2f((unsigned short)(u2 & 0xffff)), d2 = bf2f((unsigned short)(u2 >> 16));
            float x1 = bf2f((unsigned short)(u1 & 0xffff)), d1 = bf2f((unsigned short)(u1 >> 16));
            float x0 = bf2f((unsigned short)(u0 & 0xffff)), d0 = bf2f((unsigned short)(u0 >> 16));
            float B3 = Bp[(j+3)*DS];
            float B2 = Bp[(j+2)*DS];
            float B1 = Bp[(j+1)*DS];
            float B0 = Bp[(j+0)*DS];
            float e;
            e = __expf(a * S_run); H = fmaf(e * d3 * x3, B3, H); S_run += d3;
            e = __expf(a * S_run); H = fmaf(e * d2 * x2, B2, H); S_run += d2;
            e = __expf(a * S_run); H = fmaf(e * d1 * x1, B1, H); S_run += d1;
            e = __expf(a * S_run); H = fmaf(e * d0 * x0, B0, H); S_run += d0;
            if (__all(a * S_run < THR)) break;
        }
    }
    if (H != 0.f)
        atomicAdd(hlast + (((size_t)b * DS + s) * DI + d), H);
}

// ---------------------------------------------------------------- K4: the t = L-1 tail
__global__ __launch_bounds__(256) void k4_final(
    const float* __restrict__ z, const float* __restrict__ emb_w,
    const float* __restrict__ emb_b, const float* __restrict__ in_proj_w,
    const float* __restrict__ conv_w, const float* __restrict__ conv_b,
    const float* __restrict__ x_proj_w, const float* __restrict__ D_skip,
    const float* __restrict__ out_proj_w, const float* __restrict__ norm_w,
    const float* __restrict__ norm_b, const float* __restrict__ cls_w,
    const float* __restrict__ cls_b, const float* __restrict__ W1,
    const float* __restrict__ b1, const float* __restrict__ h_last,
    float* __restrict__ out)
{
    __shared__ float zl[4][64];
    __shared__ float xlast[DI];
    __shared__ float xemb[DM];
    __shared__ float Cl[DS];
    __shared__ float ylds[DI];
    __shared__ float olds[DM];
    int b = blockIdx.x, tid = threadIdx.x;
    {
        int r = tid >> 6, k = tid & 63;
        zl[r][k] = z[((size_t)b * L_ + (L_ - 4 + r)) * LAT + k];
    }
    __syncthreads();
    {   // x at t = L-1 (conv over last 4 x_pre)
        int d = tid;
        const float* wr = W1 + d * LAT;
        float xp[4];
        #pragma unroll
        for (int r = 0; r < 4; ++r) {
            float acc = b1[d];
            for (int k = 0; k < LAT; ++k) acc += zl[r][k] * wr[k];
            xp[r] = acc;
        }
        float4 cwv = *(const float4*)(conv_w + d * 4);
        float xc = cwv.x*xp[0] + cwv.y*xp[1] + cwv.z*xp[2] + cwv.w*xp[3] + conv_b[d];
        xlast[d] = siluf(xc);
    }
    __syncthreads();
    if (tid < DS) {   // C at L-1
        float acc = 0.f;
        const float* wr = x_proj_w + (size_t)(DR + DS + tid) * DI;
        for (int k = 0; k < DI; ++k) acc += xlast[k] * wr[k];
        Cl[tid] = acc;
    }
    if (tid >= 64 && tid < 64 + DM) {   // x_emb at L-1 (for z-branch)
        int m = tid - 64;
        float acc = emb_b[m];
        const float* wr = emb_w + (size_t)m * LAT;
        for (int k = 0; k < LAT; ++k) acc += zl[3][k] * wr[k];
        xemb[m] = acc;
    }
    __syncthreads();
    {   // y = (h.C) + x*D_skip, gated by silu(z-branch)
        int d = tid;
        float hs = 0.f;
        #pragma unroll
        for (int si = 0; si < DS; ++si)
            hs += h_last[((size_t)b * DS + si) * DI + d] * Cl[si];
        float y = hs + xlast[d] * D_skip[d];
        float zbv = 0.f;
        const float* wr = in_proj_w + (size_t)(DI + d) * DM;
        for (int m = 0; m < DM; ++m) zbv += xemb[m] * wr[m];
        y *= siluf(zbv);
        ylds[d] = y;
    }
    __syncthreads();
    if (tid < DM) {   // out_proj
        float acc = 0.f;
        const float* wr = out_proj_w + (size_t)tid * DI;
        for (int k = 0; k < DI; ++k) acc += ylds[k] * wr[k];
        olds[tid] = acc;
    }
    __syncthreads();
    if (tid < 64) {   // LayerNorm + classifier (one wave)
        float v0 = olds[tid], v1 = olds[tid + 64];
        float sum = v0 + v1;
        #pragma unroll
        for (int off = 32; off > 0; off >>= 1) sum += __shfl_down(sum, off);
        float mu = __shfl(sum, 0) * (1.0f / 128.0f);
        float dv0 = v0 - mu, dv1 = v1 - mu;
        float vs = dv0 * dv0 + dv1 * dv1;
        #pragma unroll
        for (int off = 32; off > 0; off >>= 1) vs += __shfl_down(vs, off);
        float var = __shfl(vs, 0) * (1.0f / 128.0f);
        float rstd = rsqrtf(var + 1e-5f);
        float xn0 = dv0 * rstd * norm_w[tid] + norm_b[tid];
        float xn1 = dv1 * rstd * norm_w[tid + 64] + norm_b[tid + 64];
        float lg = xn0 * cls_w[tid] + xn1 * cls_w[tid + 64];
        #pragma unroll
        for (int off = 32; off > 0; off >>= 1) lg += __shfl_down(lg, off);
        if (tid == 0) out[b] = lg + cls_b[0];
    }
}

// ---------------------------------------------------------------- launch
extern "C" void kernel_launch(void* const* d_in, const int* in_sizes, int n_in,
                              void* d_out, int out_size, void* d_ws, size_t ws_size,
                              hipStream_t stream) {
    (void)in_sizes; (void)n_in; (void)out_size;
    const float* z         = (const float*)d_in[0];
    const float* emb_w     = (const float*)d_in[1];
    const float* emb_b     = (const float*)d_in[2];
    const float* in_proj_w = (const float*)d_in[3];
    const float* conv_w    = (const float*)d_in[4];
    const float* conv_b    = (const float*)d_in[5];
    const float* x_proj_w  = (const float*)d_in[6];
    const float* dt_proj_w = (const float*)d_in[7];
    const float* dt_proj_b = (const float*)d_in[8];
    const float* A_log     = (const float*)d_in[9];
    const float* D_skip    = (const float*)d_in[10];
    const float* out_proj_w= (const float*)d_in[11];
    const float* norm_w    = (const float*)d_in[12];
    const float* norm_b    = (const float*)d_in[13];
    const float* cls_w     = (const float*)d_in[14];
    const float* cls_b     = (const float*)d_in[15];
    float* out = (float*)d_out;

    float* ws    = (float*)d_ws;
    float* W1    = ws;                       // 16384 f
    float* b1    = W1 + 16384;               // 256 f
    float* Bssm  = b1 + 256;                 // 16*3600*16  = 921600 f
    float* Dcs   = Bssm + 921600;            // 16*80*256   = 327680 f
    float* Rsuf  = Dcs + 327680;             // 327680 f
    float* hlast = Rsuf + 327680;            // 16*16*256   = 65536 f
    float* fend  = hlast + 65536;
    unsigned short* W1h  = (unsigned short*)fend;             // 16384 u16
    unsigned short* W1l  = W1h + 16384;                       // 16384 u16
    unsigned short* xwh  = W1l + 16384;                       // 24*256 = 6144 u16
    unsigned short* xwl  = xwh + 6144;                        // 6144 u16
    unsigned int*   xd   = (unsigned int*)(xwl + 6144);       // 16*3600*256 u32 (x lo, dt hi)
    size_t needed = ((size_t)(16384 + 256 + 921600 + 327680 + 327680 + 65536)) * 4
                  + ((size_t)(16384 + 16384 + 6144 + 6144)) * 2
                  + (size_t)B_ * L_ * DI * 4;
    if (ws_size < needed) return;

    k0_combine <<<dim3(DI + 24),     dim3(LAT), 0, stream>>>(in_proj_w, emb_w, emb_b, x_proj_w,
                                                             W1, b1, W1h, W1l, xwh, xwl);
    k1_front   <<<dim3(NT, B_),      dim3(256), 0, stream>>>(z, conv_w, conv_b, dt_proj_w, dt_proj_b,
                                                             W1h, W1l, xwh, xwl, b1,
                                                             Bssm, Dcs, xd, hlast);
    k3a2_suffix<<<dim3(B_),          dim3(256), 0, stream>>>(Dcs, Rsuf);
    k3b_scan   <<<dim3(NC, 8, B_),   dim3(512), 0, stream>>>(xd, Bssm, A_log, Rsuf, hlast);
    k4_final   <<<dim3(B_),          dim3(256), 0, stream>>>(z, emb_w, emb_b, in_proj_w, conv_w, conv_b,
                                                             x_proj_w, D_skip, out_proj_w, norm_w, norm_b,
                                                             cls_w, cls_b, W1, b1, hlast, out);
}

// Round 10
// 110.469 us; speedup vs baseline: 2.1725x; 1.0574x over previous
//
#include <hip/hip_runtime.h>
#include <hip/hip_bf16.h>
#include <math.h>

#define B_  16
#define L_  3600
#define LAT 64
#define DM  128
#define DI  256
#define DS  16
#define DR  8

#define TT  45    // K1 time-tile == scan chunk length
#define NT  80    // 3600/45 tiles == chunks
#define NC  80
#define TC  45
#define THR (-20.0f)   // exp(a*S) < exp(-20) ~ 2e-9 -> negligible

typedef __bf16 v8bf __attribute__((ext_vector_type(8)));
typedef float  v4f  __attribute__((ext_vector_type(4)));
typedef unsigned short v8us __attribute__((ext_vector_type(8)));

#define MFMA16(A, Bf, C) __builtin_amdgcn_mfma_f32_16x16x32_bf16((A), (Bf), (C), 0, 0, 0)

__device__ __forceinline__ float siluf(float v) {
    return v * __builtin_amdgcn_rcpf(1.0f + __expf(-v));
}
__device__ __forceinline__ float softplusf(float v) {
    float r = __logf(1.0f + __expf(v));
    return (v > 15.0f) ? v : r;
}
__device__ __forceinline__ float bf2f(unsigned short u) {
    unsigned int x = ((unsigned int)u) << 16;
    return __builtin_bit_cast(float, x);
}
__device__ __forceinline__ unsigned short f2bf(float f) {
    __hip_bfloat16 h = __float2bfloat16(f);
    return __builtin_bit_cast(unsigned short, h);
}

// ---------------------------------------------------------------- K0: W1 = in_proj_x @ emb_w (+ hi/lo bf16), b1; pre-swizzled x_proj hi/lo
__global__ __launch_bounds__(64) void k0_combine(
    const float* __restrict__ in_proj_w, const float* __restrict__ emb_w,
    const float* __restrict__ emb_b, const float* __restrict__ x_proj_w,
    float* __restrict__ W1, float* __restrict__ b1,
    unsigned short* __restrict__ W1h, unsigned short* __restrict__ W1l,
    unsigned short* __restrict__ xwh, unsigned short* __restrict__ xwl)
{
    int blk = blockIdx.x, k = threadIdx.x;
    if (blk < DI) {
        int d = blk;
        const float* row = in_proj_w + (size_t)d * DM;
        float acc = 0.f;
        for (int m = 0; m < DM; ++m) acc += row[m] * emb_w[m * LAT + k];
        W1[d * LAT + k] = acc;
        unsigned short h = f2bf(acc);
        W1h[d * LAT + k] = h;
        W1l[d * LAT + k] = f2bf(acc - bf2f(h));
        if (k == 0) {
            float ab = 0.f;
            for (int m = 0; m < DM; ++m) ab += row[m] * emb_b[m];
            b1[d] = ab;
        }
    } else {
        int j = blk - DI;   // 0..23
        int sw = (j & 7) << 3;
        #pragma unroll
        for (int q = 0; q < 4; ++q) {
            int c = k * 4 + q;
            float v = x_proj_w[(size_t)j * DI + c];
            unsigned short h = f2bf(v);
            int idx = j * 256 + (c ^ sw);
            xwh[idx] = h;
            xwl[idx] = f2bf(v - bf2f(h));
        }
    }
}

// ---------------------------------------------------------------- K1: MFMA front-end + dt + chunk dt-sums
// 1 tile/block, 1280 blocks; LDS 33,280 B; launch_bounds(256,3).
// CRITICAL (round-10 fix): phase C is FULLY unrolled so xr[t] is statically
// indexed -> xr stays in registers/AGPRs. The previous `#pragma unroll 5`
// made t a runtime index, demoting xr[45] to scratch: exactly +57.6 MB
// WRITE_SIZE (45*256*1280*4B) and +20 MB FETCH on every dispatch (rounds 4-9).
// LDS byte map (smem region):
//   phase A/conv : [0,16448) xpre f32[16][257] | [16448,22592) z-hi | [22592,28736) z-lo
//   phase B      : [0,24576) xt16 u16[48][256] swz (xw frags read from GLOBAL, L2-hot)
// Bssm staged in bl[45][16] LDS, written coalesced in phase C.
__global__ __launch_bounds__(256, 3) void k1_front(
    const float* __restrict__ z, const float* __restrict__ conv_w,
    const float* __restrict__ conv_b, const float* __restrict__ dt_proj_w,
    const float* __restrict__ dt_proj_b,
    const unsigned short* __restrict__ W1h, const unsigned short* __restrict__ W1l,
    const unsigned short* __restrict__ xwh, const unsigned short* __restrict__ xwl,
    const float* __restrict__ b1,
    float* __restrict__ Bssm, float* __restrict__ Dcs,
    unsigned int* __restrict__ xd, float* __restrict__ hlast)
{
    __shared__ __align__(16) unsigned char smem[28736];
    __shared__ float dtl[TT][8];
    __shared__ float bl[TT][DS];
    float* xpre = (float*)smem;                              // [16][257] f32
    unsigned short* zth = (unsigned short*)(smem + 16448);   // 3072 u16
    unsigned short* ztl = (unsigned short*)(smem + 22592);   // 3072 u16
    unsigned short* xt16 = (unsigned short*)smem;            // [48][256] swz

    int b = blockIdx.y, tile = blockIdx.x;
    int t0 = tile * TT;
    int t0m3 = t0 - 3;
    int tid = threadIdx.x;
    int lane = tid & 63, wid = tid >> 6;
    int l15 = lane & 15, l4 = lane >> 4;

    // zero hlast (poisoned workspace) -- before k3b runs
    if (tile == 0) {
        float4 z4 = make_float4(0.f, 0.f, 0.f, 0.f);
        float4* hl4 = (float4*)(hlast + (size_t)b * (DS * DI));
        #pragma unroll
        for (int i = 0; i < 4; ++i) hl4[tid + i * 256] = z4;
    }

    // per-thread conv + dt params (channel d = tid)
    float4 cw = *(const float4*)(conv_w + tid * 4);
    float cb = conv_b[tid];
    float bias = b1[tid];
    float4 dwA = *(const float4*)(dt_proj_w + (size_t)tid * DR);
    float4 dwB = *(const float4*)(dt_proj_w + (size_t)tid * DR + 4);
    float dbias = dt_proj_b[tid];

    // ---- B-frags for phase A from W1 hi/lo (once per block)
    v8bf wh[4][2], wl[4][2];
    int d0w = wid * 64;
    {
        #pragma unroll
        for (int nt = 0; nt < 4; ++nt) {
            int dr = d0w + nt * 16 + l15;
            #pragma unroll
            for (int kb = 0; kb < 2; ++kb) {
                int k0 = kb * 32 + l4 * 8;
                wh[nt][kb] = __builtin_bit_cast(v8bf, *(const v8us*)(W1h + (size_t)dr * LAT + k0));
                wl[nt][kb] = __builtin_bit_cast(v8bf, *(const v8us*)(W1l + (size_t)dr * LAT + k0));
            }
        }
    }

    // ---- stage z tile (48 rows incl history) as hi/lo bf16, XOR-swizzled rows
    {
        const float* zb = z + (size_t)b * L_ * LAT;
        for (int i = tid; i < 48 * 8; i += 256) {   // (row, 8-elem slot)
            int r = i >> 3, s = i & 7;
            int tg = t0m3 + r;
            float f[8];
            if (tg >= 0) {
                float4 u = *(const float4*)(zb + (size_t)tg * LAT + s * 8);
                float4 v = *(const float4*)(zb + (size_t)tg * LAT + s * 8 + 4);
                f[0]=u.x; f[1]=u.y; f[2]=u.z; f[3]=u.w; f[4]=v.x; f[5]=v.y; f[6]=v.z; f[7]=v.w;
            } else {
                #pragma unroll
                for (int q = 0; q < 8; ++q) f[q] = 0.f;
            }
            v8us hh, ll;
            #pragma unroll
            for (int q = 0; q < 8; ++q) {
                unsigned short h = f2bf(f[q]);
                hh[q] = h;
                ll[q] = f2bf(f[q] - bf2f(h));
            }
            int idx = r * 64 + ((s * 8) ^ ((r & 7) << 3));   // u16 units, 16B slots
            *(v8us*)&zth[idx] = hh;
            *(v8us*)&ztl[idx] = ll;
        }
    }
    __syncthreads();

    float xr[TT];
    float p0 = 0.f, p1 = 0.f, p2 = 0.f;

    // ---- phase A in 3 sub-phases of 16 rows: MFMA(mt) -> bar -> conv -> bar
    #pragma unroll
    for (int mt = 0; mt < 3; ++mt) {
        {   // MFMA m-tile mt (writes xpre rows 0..15)
            int r = mt * 16 + l15;
            int sw = (r & 7) << 3;
            int kb0 = l4 * 8;
            v8bf ah0 = __builtin_bit_cast(v8bf, *(const v8us*)&zth[r * 64 + (kb0 ^ sw)]);
            v8bf ah1 = __builtin_bit_cast(v8bf, *(const v8us*)&zth[r * 64 + ((32 + kb0) ^ sw)]);
            v8bf al0 = __builtin_bit_cast(v8bf, *(const v8us*)&ztl[r * 64 + (kb0 ^ sw)]);
            v8bf al1 = __builtin_bit_cast(v8bf, *(const v8us*)&ztl[r * 64 + ((32 + kb0) ^ sw)]);
            int rr = l4 * 4;
            #pragma unroll
            for (int nt = 0; nt < 4; ++nt) {
                v4f acc = {0.f, 0.f, 0.f, 0.f};
                acc = MFMA16(ah0, wh[nt][0], acc);
                acc = MFMA16(ah1, wh[nt][1], acc);
                acc = MFMA16(ah0, wl[nt][0], acc);
                acc = MFMA16(ah1, wl[nt][1], acc);
                acc = MFMA16(al0, wh[nt][0], acc);
                acc = MFMA16(al1, wh[nt][1], acc);
                int cc = d0w + nt * 16 + l15;
                xpre[(rr + 0) * 257 + cc] = acc[0];
                xpre[(rr + 1) * 257 + cc] = acc[1];
                xpre[(rr + 2) * 257 + cc] = acc[2];
                xpre[(rr + 3) * 257 + cc] = acc[3];
            }
        }
        __syncthreads();
        {   // conv rows mt*16 .. mt*16+15
            int d = tid;
            if (mt == 0) {
                p0 = xpre[0 * 257 + d] + ((t0m3 + 0 >= 0) ? bias : 0.f);
                p1 = xpre[1 * 257 + d] + ((t0m3 + 1 >= 0) ? bias : 0.f);
                p2 = xpre[2 * 257 + d] + ((t0m3 + 2 >= 0) ? bias : 0.f);
                #pragma unroll
                for (int r = 3; r < 16; ++r) {
                    float cur = xpre[r * 257 + d] + bias;
                    float xc = cw.x * p0 + cw.y * p1 + cw.z * p2 + cw.w * cur + cb;
                    xr[r - 3] = siluf(xc);
                    p0 = p1; p1 = p2; p2 = cur;
                }
            } else {
                int rbase = mt * 16;
                #pragma unroll
                for (int q = 0; q < 16; ++q) {
                    float cur = xpre[q * 257 + d] + bias;
                    float xc = cw.x * p0 + cw.y * p1 + cw.z * p2 + cw.w * cur + cb;
                    xr[rbase + q - 3] = siluf(xc);
                    p0 = p1; p1 = p2; p2 = cur;
                }
            }
        }
        __syncthreads();
    }

    // ---- write xt bf16 (swizzled; xpre & z-tile now dead)
    {
        int d = tid;
        #pragma unroll
        for (int t = 0; t < TT; ++t)
            xt16[t * 256 + (d ^ ((t & 7) << 3))] = f2bf(xr[t]);
        #pragma unroll
        for (int t = TT; t < 48; ++t)
            xt16[t * 256 + (d ^ ((t & 7) << 3))] = 0;
    }
    __syncthreads();

    // ---- phase B MFMA: x_dbl[t][j] = sum_k xt[t][k] * x_proj_w[j][k], j = 0..23
    //      B-frags (xw hi/lo) read directly from GLOBAL (pre-swizzled by k0; 24 KB, L2-hot)
    if (wid < 3) {
        int mt = wid;
        int rA = mt * 16 + l15;
        int swA = (rA & 7) << 3;
        int jc0 = l15;
        int jc1 = 16 + l15; if (jc1 > 23) jc1 = 23;   // clamp (outputs >=24 discarded)
        v4f acc0 = {0.f, 0.f, 0.f, 0.f}, acc1 = {0.f, 0.f, 0.f, 0.f};
        #pragma unroll
        for (int kb = 0; kb < 8; ++kb) {
            int k0 = kb * 32 + l4 * 8;
            v8bf xa  = __builtin_bit_cast(v8bf, *(const v8us*)&xt16[rA * 256 + (k0 ^ swA)]);
            int s0 = k0 ^ ((jc0 & 7) << 3);
            int s1 = k0 ^ ((jc1 & 7) << 3);
            v8bf b0h = __builtin_bit_cast(v8bf, *(const v8us*)(xwh + jc0 * 256 + s0));
            v8bf b0l = __builtin_bit_cast(v8bf, *(const v8us*)(xwl + jc0 * 256 + s0));
            v8bf b1h = __builtin_bit_cast(v8bf, *(const v8us*)(xwh + jc1 * 256 + s1));
            v8bf b1l = __builtin_bit_cast(v8bf, *(const v8us*)(xwl + jc1 * 256 + s1));
            acc0 = MFMA16(xa, b0h, acc0);
            acc0 = MFMA16(xa, b0l, acc0);
            acc1 = MFMA16(xa, b1h, acc1);
            acc1 = MFMA16(xa, b1l, acc1);
        }
        int rr = mt * 16 + l4 * 4;
        #pragma unroll
        for (int reg = 0; reg < 4; ++reg) {
            int t = rr + reg;
            if (t < TT) {
                float v0 = acc0[reg], v1 = acc1[reg];
                if (l15 < 8) {
                    dtl[t][l15] = v0;          // dt_in cols 0..7
                    bl[t][8 + l15] = v1;       // B cols 8..15 (j = 16..23)
                } else {
                    bl[t][l15 - 8] = v0;       // B cols 0..7 (j = 8..15)
                }
            }
        }
    }
    __syncthreads();

    // ---- phase C: Bssm coalesced store (from bl) + dt = softplus(...) packed store + per-tile sum
    {
        // coalesced Bssm: 720 consecutive floats, 256B per wave-store
        float* Bout = Bssm + ((size_t)b * L_ + t0) * DS;
        #pragma unroll
        for (int i = tid; i < TT * DS; i += 256)
            Bout[i] = bl[i >> 4][i & 15];

        int d = tid;
        unsigned int* xdout = xd + ((size_t)b * L_ + t0) * DI + d;
        float S = 0.f;
        #pragma unroll    // FULL unroll: static xr[t] indices keep xr in registers (no scratch)
        for (int t = 0; t < TT; ++t) {
            float4 u = *(const float4*)&dtl[t][0];
            float4 v = *(const float4*)&dtl[t][4];
            float r = dbias + u.x*dwA.x + u.y*dwA.y + u.z*dwA.z + u.w*dwA.w
                            + v.x*dwB.x + v.y*dwB.y + v.z*dwB.z + v.w*dwB.w;
            float dt = softplusf(r);
            unsigned int pack = ((unsigned int)f2bf(dt) << 16) | (unsigned int)f2bf(xr[t]);
            xdout[(size_t)t * DI] = pack;
            S += dt;
        }
        Dcs[((size_t)b * NC + tile) * DI + d] = S;
    }
}

// ---------------------------------------------------------------- K3a2: suffix sums of chunk dt-sums (register-preloaded, no serial load chain)
__global__ __launch_bounds__(256) void k3a2_suffix(
    const float* __restrict__ Dcs, float* __restrict__ Rsuf)
{
    int b = blockIdx.x, d = threadIdx.x;
    const float* src = Dcs + (size_t)b * NC * DI + d;
    float* dst = Rsuf + (size_t)b * NC * DI + d;
    float v[40];
    float R = 0.f;
    // upper half: c = 79..40
    #pragma unroll
    for (int i = 0; i < 40; ++i) v[i] = src[(size_t)(NC - 1 - i) * DI];
    #pragma unroll
    for (int i = 0; i < 40; ++i) { dst[(size_t)(NC - 1 - i) * DI] = R; R += v[i]; }
    // lower half: c = 39..0
    #pragma unroll
    for (int i = 0; i < 40; ++i) v[i] = src[(size_t)(39 - i) * DI];
    #pragma unroll
    for (int i = 0; i < 40; ++i) { dst[(size_t)(39 - i) * DI] = R; R += v[i]; }
}

// ---------------------------------------------------------------- K3b: streaming suffix reduction; atomic combine into hlast
__global__ __launch_bounds__(512) void k3b_scan(
    const unsigned int* __restrict__ xd,
    const float* __restrict__ Bssm, const float* __restrict__ A_log,
    const float* __restrict__ Rsuf, float* __restrict__ hlast)
{
    int c = blockIdx.x, dg = blockIdx.y, b = blockIdx.z;
    int tid = threadIdx.x;
    int dh = tid & 31;
    int s  = ((tid >> 6) << 1) | ((tid >> 5) & 1);
    int d  = dg * 32 + dh;

    float a = -__expf(A_log[d * DS + s]);
    float R = Rsuf[((size_t)b * NC + c) * DI + d];

    float H = 0.f;
    float S_run = R;
    if (!__all(a * R < THR)) {
        int t0 = c * TC;
        const unsigned int* xp = xd + ((size_t)b * L_ + t0) * DI + d;
        const float* Bp = Bssm + ((size_t)b * L_ + t0) * DS + s;
        {   // t = TT-1 single (45 = 11*4 + 1)
            unsigned int u4 = xp[(TC-1)*DI];
            float x4 = bf2f((unsigned short)(u4 & 0xffff));
            float d4 = bf2f((unsigned short)(u4 >> 16));
            float B4 = Bp[(TC-1)*DS];
            float e = __expf(a * S_run); H = fmaf(e * d4 * x4, B4, H); S_run += d4;
        }
        for (int j = TC - 5; j >= 0; j -= 4) {
            unsigned int u3 = xp[(j+3)*DI];
            unsigned int u2 = xp[(j+2)*DI];
            unsigned int u1 = xp[(j+1)*DI];
            unsigned int u0 = xp[(j+0)*DI];
            float x3 = bf2f((unsigned short)(u3 & 0xffff)), d3 = bf2f((unsigned short)(u3 >> 16));
            float x2 = bf2f((unsigned short)(u2 & 0xffff)), d2 = bf2f((unsigned short)(u2 >> 16));
            float x1 = bf2f((unsigned short)(u1 & 0xffff)), d1 = bf2f((unsigned short)(u1 >> 16));
            float x0 = bf2f((unsigned short)(u0 & 0xffff)), d0 = bf2f((unsigned short)(u0 >> 16));
            float B3 = Bp[(j+3)*DS];
            float B2 = Bp[(j+2)*DS];
            float B1 = Bp[(j+1)*DS];
            float B0 = Bp[(j+0)*DS];
            float e;
            e = __expf(a * S_run); H = fmaf(e * d3 * x3, B3, H); S_run += d3;
            e = __expf(a * S_run); H = fmaf(e * d2 * x2, B2, H); S_run += d2;
            e = __expf(a * S_run); H = fmaf(e * d1 * x1, B1, H); S_run += d1;
            e = __expf(a * S_run); H = fmaf(e * d0 * x0, B0, H); S_run += d0;
            if (__all(a * S_run < THR)) break;
        }
    }
    if (H != 0.f)
        atomicAdd(hlast + (((size_t)b * DS + s) * DI + d), H);
}

// ---------------------------------------------------------------- K4: the t = L-1 tail
__global__ __launch_bounds__(256) void k4_final(
    const float* __restrict__ z, const float* __restrict__ emb_w,
    const float* __restrict__ emb_b, const float* __restrict__ in_proj_w,
    const float* __restrict__ conv_w, const float* __restrict__ conv_b,
    const float* __restrict__ x_proj_w, const float* __restrict__ D_skip,
    const float* __restrict__ out_proj_w, const float* __restrict__ norm_w,
    const float* __restrict__ norm_b, const float* __restrict__ cls_w,
    const float* __restrict__ cls_b, const float* __restrict__ W1,
    const float* __restrict__ b1, const float* __restrict__ h_last,
    float* __restrict__ out)
{
    __shared__ float zl[4][64];
    __shared__ float xlast[DI];
    __shared__ float xemb[DM];
    __shared__ float Cl[DS];
    __shared__ float ylds[DI];
    __shared__ float olds[DM];
    int b = blockIdx.x, tid = threadIdx.x;
    {
        int r = tid >> 6, k = tid & 63;
        zl[r][k] = z[((size_t)b * L_ + (L_ - 4 + r)) * LAT + k];
    }
    __syncthreads();
    {   // x at t = L-1 (conv over last 4 x_pre)
        int d = tid;
        const float* wr = W1 + d * LAT;
        float xp[4];
        #pragma unroll
        for (int r = 0; r < 4; ++r) {
            float acc = b1[d];
            for (int k = 0; k < LAT; ++k) acc += zl[r][k] * wr[k];
            xp[r] = acc;
        }
        float4 cwv = *(const float4*)(conv_w + d * 4);
        float xc = cwv.x*xp[0] + cwv.y*xp[1] + cwv.z*xp[2] + cwv.w*xp[3] + conv_b[d];
        xlast[d] = siluf(xc);
    }
    __syncthreads();
    if (tid < DS) {   // C at L-1
        float acc = 0.f;
        const float* wr = x_proj_w + (size_t)(DR + DS + tid) * DI;
        for (int k = 0; k < DI; ++k) acc += xlast[k] * wr[k];
        Cl[tid] = acc;
    }
    if (tid >= 64 && tid < 64 + DM) {   // x_emb at L-1 (for z-branch)
        int m = tid - 64;
        float acc = emb_b[m];
        const float* wr = emb_w + (size_t)m * LAT;
        for (int k = 0; k < LAT; ++k) acc += zl[3][k] * wr[k];
        xemb[m] = acc;
    }
    __syncthreads();
    {   // y = (h.C) + x*D_skip, gated by silu(z-branch)
        int d = tid;
        float hs = 0.f;
        #pragma unroll
        for (int si = 0; si < DS; ++si)
            hs += h_last[((size_t)b * DS + si) * DI + d] * Cl[si];
        float y = hs + xlast[d] * D_skip[d];
        float zbv = 0.f;
        const float* wr = in_proj_w + (size_t)(DI + d) * DM;
        for (int m = 0; m < DM; ++m) zbv += xemb[m] * wr[m];
        y *= siluf(zbv);
        ylds[d] = y;
    }
    __syncthreads();
    if (tid < DM) {   // out_proj
        float acc = 0.f;
        const float* wr = out_proj_w + (size_t)tid * DI;
        for (int k = 0; k < DI; ++k) acc += ylds[k] * wr[k];
        olds[tid] = acc;
    }
    __syncthreads();
    if (tid < 64) {   // LayerNorm + classifier (one wave)
        float v0 = olds[tid], v1 = olds[tid + 64];
        float sum = v0 + v1;
        #pragma unroll
        for (int off = 32; off > 0; off >>= 1) sum += __shfl_down(sum, off);
        float mu = __shfl(sum, 0) * (1.0f / 128.0f);
        float dv0 = v0 - mu, dv1 = v1 - mu;
        float vs = dv0 * dv0 + dv1 * dv1;
        #pragma unroll
        for (int off = 32; off > 0; off >>= 1) vs += __shfl_down(vs, off);
        float var = __shfl(vs, 0) * (1.0f / 128.0f);
        float rstd = rsqrtf(var + 1e-5f);
        float xn0 = dv0 * rstd * norm_w[tid] + norm_b[tid];
        float xn1 = dv1 * rstd * norm_w[tid + 64] + norm_b[tid + 64];
        float lg = xn0 * cls_w[tid] + xn1 * cls_w[tid + 64];
        #pragma unroll
        for (int off = 32; off > 0; off >>= 1) lg += __shfl_down(lg, off);
        if (tid == 0) out[b] = lg + cls_b[0];
    }
}

// ---------------------------------------------------------------- launch
extern "C" void kernel_launch(void* const* d_in, const int* in_sizes, int n_in,
                              void* d_out, int out_size, void* d_ws, size_t ws_size,
                              hipStream_t stream) {
    (void)in_sizes; (void)n_in; (void)out_size;
    const float* z         = (const float*)d_in[0];
    const float* emb_w     = (const float*)d_in[1];
    const float* emb_b     = (const float*)d_in[2];
    const float* in_proj_w = (const float*)d_in[3];
    const float* conv_w    = (const float*)d_in[4];
    const float* conv_b    = (const float*)d_in[5];
    const float* x_proj_w  = (const float*)d_in[6];
    const float* dt_proj_w = (const float*)d_in[7];
    const float* dt_proj_b = (const float*)d_in[8];
    const float* A_log     = (const float*)d_in[9];
    const float* D_skip    = (const float*)d_in[10];
    const float* out_proj_w= (const float*)d_in[11];
    const float* norm_w    = (const float*)d_in[12];
    const float* norm_b    = (const float*)d_in[13];
    const float* cls_w     = (const float*)d_in[14];
    const float* cls_b     = (const float*)d_in[15];
    float* out = (float*)d_out;

    float* ws    = (float*)d_ws;
    float* W1    = ws;                       // 16384 f
    float* b1    = W1 + 16384;               // 256 f
    float* Bssm  = b1 + 256;                 // 16*3600*16  = 921600 f
    float* Dcs   = Bssm + 921600;            // 16*80*256   = 327680 f
    float* Rsuf  = Dcs + 327680;             // 327680 f
    float* hlast = Rsuf + 327680;            // 16*16*256   = 65536 f
    float* fend  = hlast + 65536;
    unsigned short* W1h  = (unsigned short*)fend;             // 16384 u16
    unsigned short* W1l  = W1h + 16384;                       // 16384 u16
    unsigned short* xwh  = W1l + 16384;                       // 24*256 = 6144 u16
    unsigned short* xwl  = xwh + 6144;                        // 6144 u16
    unsigned int*   xd   = (unsigned int*)(xwl + 6144);       // 16*3600*256 u32 (x lo, dt hi)
    size_t needed = ((size_t)(16384 + 256 + 921600 + 327680 + 327680 + 65536)) * 4
                  + ((size_t)(16384 + 16384 + 6144 + 6144)) * 2
                  + (size_t)B_ * L_ * DI * 4;
    if (ws_size < needed) return;

    k0_combine <<<dim3(DI + 24),     dim3(LAT), 0, stream>>>(in_proj_w, emb_w, emb_b, x_proj_w,
                                                             W1, b1, W1h, W1l, xwh, xwl);
    k1_front   <<<dim3(NT, B_),      dim3(256), 0, stream>>>(z, conv_w, conv_b, dt_proj_w, dt_proj_b,
                                                             W1h, W1l, xwh, xwl, b1,
                                                             Bssm, Dcs, xd, hlast);
    k3a2_suffix<<<dim3(B_),          dim3(256), 0, stream>>>(Dcs, Rsuf);
    k3b_scan   <<<dim3(NC, 8, B_),   dim3(512), 0, stream>>>(xd, Bssm, A_log, Rsuf, hlast);
    k4_final   <<<dim3(B_),          dim3(256), 0, stream>>>(z, emb_w, emb_b, in_proj_w, conv_w, conv_b,
                                                             x_proj_w, D_skip, out_proj_w, norm_w, norm_b,
                                                             cls_w, cls_b, W1, b1, hlast, out);
}